// Round 1
// baseline (1625.021 us; speedup 1.0000x reference)
//
#include <hip/hip_runtime.h>
#include <stdint.h>

#define DEVI __device__ __forceinline__

typedef __attribute__((ext_vector_type(8))) short short8;
typedef __attribute__((ext_vector_type(4))) short short4v;
typedef __attribute__((ext_vector_type(4))) float f32x4;

DEVI float bf2f(short s) { union { float f; uint32_t u; } x; x.u = ((uint32_t)(uint16_t)s) << 16; return x.f; }
DEVI short f2bf(float f) { union { float f; uint32_t u; } x; x.f = f; uint32_t r = x.u + 0x7fffu + ((x.u >> 16) & 1u); return (short)(r >> 16); }

// ---------------------------------------------------------------------------
// Generic 64x128-tile bf16 MFMA GEMM: out = epi(A[M,K] @ Bt[N,K]^T)
// A row-major [M][K] bf16; Bt is transposed weights [N][K] bf16.
// Tile: 64 rows x 128 cols per block; 4 waves, wave w owns rows w*16..w*16+15.
// LDS granule XOR swizzle (g ^= row&15) keeps ds_read_b128 frag fetches 2-way.
// Epilogues: bias / relu / residual+LN(128) / fp32 and-or bf16 stores.
// ---------------------------------------------------------------------------
template<bool HB, bool RELU, bool LN, bool RES, bool OF, bool OB>
__global__ __launch_bounds__(256) void gemm_epi(
    const short* __restrict__ A, const short* __restrict__ Bt,
    int M, int K,
    const float* __restrict__ bias,
    const short* __restrict__ res16,
    const float* __restrict__ gamma, const float* __restrict__ beta,
    float* __restrict__ outF, int ldF,
    short* __restrict__ out16, int ld16)
{
    __shared__ char smem[49152];
    short* ldsA = (short*)smem;            // [64][128] shorts, swizzled granules
    short* ldsB = (short*)(smem + 16384);  // [128][128]
    float* ldsE = (float*)smem;            // epilogue [64][132]

    const int tid = threadIdx.x;
    const int w = tid >> 6, l = tid & 63;
    const int quad = l >> 4, n16 = l & 15;
    const int m0 = blockIdx.x * 64;
    const int n0 = blockIdx.y * 128;

    f32x4 acc[8];
#pragma unroll
    for (int i = 0; i < 8; ++i) { f32x4 zz = {0.f, 0.f, 0.f, 0.f}; acc[i] = zz; }

    const int nch = K >> 7;
    for (int c = 0; c < nch; ++c) {
#pragma unroll
        for (int ii = 0; ii < 4; ++ii) {
            int rl = (w * 4 + ii) * 4 + quad;
            int row = m0 + rl; if (row >= M) row = M - 1;
            int g = n16 ^ (rl & 15);
            short8 v = *(const short8*)(A + (size_t)row * K + c * 128 + g * 8);
            *(short8*)(ldsA + rl * 128 + n16 * 8) = v;
        }
#pragma unroll
        for (int jj = 0; jj < 8; ++jj) {
            int nl = (w * 8 + jj) * 4 + quad;
            int g = n16 ^ (nl & 15);
            short8 v = *(const short8*)(Bt + (size_t)(n0 + nl) * K + c * 128 + g * 8);
            *(short8*)(ldsB + nl * 128 + n16 * 8) = v;
        }
        __syncthreads();
#pragma unroll
        for (int kk = 0; kk < 4; ++kk) {
            int gi = kk * 4 + quad;
            short8 a = *(const short8*)(ldsA + (w * 16 + n16) * 128 + (gi ^ n16) * 8);
#pragma unroll
            for (int ct = 0; ct < 8; ++ct) {
                short8 b = *(const short8*)(ldsB + (ct * 16 + n16) * 128 + (gi ^ n16) * 8);
                acc[ct] = __builtin_amdgcn_mfma_f32_16x16x32_bf16(a, b, acc[ct], 0, 0, 0);
            }
        }
        __syncthreads();
    }

    // stage C tile to LDS (fp32, padded stride 132) for row-wise epilogue
#pragma unroll
    for (int ct = 0; ct < 8; ++ct)
#pragma unroll
        for (int r = 0; r < 4; ++r)
            ldsE[(w * 16 + quad * 4 + r) * 132 + ct * 16 + n16] = acc[ct][r];
    __syncthreads();

    const int rl = tid >> 2, p = tid & 3;
    const int row = m0 + rl;
    const bool valid = row < M;
    const int cb = p * 32;
    float v[32];
#pragma unroll
    for (int j = 0; j < 32; ++j) v[j] = ldsE[rl * 132 + cb + j];
    if (HB) {
#pragma unroll
        for (int j = 0; j < 32; ++j) v[j] += bias[n0 + cb + j];
    }
    if (RES) {
        if (valid) {
#pragma unroll
            for (int j = 0; j < 32; ++j) v[j] += bf2f(res16[(size_t)row * 128 + cb + j]);
        }
    }
    if (RELU) {
#pragma unroll
        for (int j = 0; j < 32; ++j) v[j] = fmaxf(v[j], 0.f);
    }
    if (LN) {  // N==128 required: full row in block
        float s = 0.f, q = 0.f;
#pragma unroll
        for (int j = 0; j < 32; ++j) { s += v[j]; q += v[j] * v[j]; }
        s += __shfl_xor(s, 1); q += __shfl_xor(q, 1);
        s += __shfl_xor(s, 2); q += __shfl_xor(q, 2);
        float mean = s * (1.f / 128.f);
        float var = q * (1.f / 128.f) - mean * mean;
        float inv = rsqrtf(var + 1e-5f);
#pragma unroll
        for (int j = 0; j < 32; ++j) v[j] = (v[j] - mean) * inv * gamma[cb + j] + beta[cb + j];
    }
    if (valid) {
        if (OF) {
#pragma unroll
            for (int jj = 0; jj < 8; ++jj) {
                f32x4 t = { v[jj*4], v[jj*4+1], v[jj*4+2], v[jj*4+3] };
                *(f32x4*)(outF + (size_t)row * ldF + n0 + cb + jj * 4) = t;
            }
        }
        if (OB) {
#pragma unroll
            for (int jj = 0; jj < 8; ++jj) {
                short4v t = { f2bf(v[jj*4]), f2bf(v[jj*4+1]), f2bf(v[jj*4+2]), f2bf(v[jj*4+3]) };
                *(short4v*)(out16 + (size_t)row * ld16 + n0 + cb + jj * 4) = t;
            }
        }
    }
}

// ---------------------------------------------------------------------------
// Edge kernel: pe = ef16 @ WeT (MFMA), then per-edge
//   score = K[src]*Q[dst]*0.25*pe  -> e_out (bf16)
//   s = exp(clip(sum_d score, -5, 5)) per head (head == col-tile ct)
//   atomics: wV[dst] += V[src]*s ; z[dst,h] += s
// ---------------------------------------------------------------------------
__global__ __launch_bounds__(256) void edge_score_k(
    const short* __restrict__ ef16, const short* __restrict__ WeT,
    const short* __restrict__ Q16, const short* __restrict__ K16, const short* __restrict__ V16,
    const int* __restrict__ srcI, const int* __restrict__ dstI,
    short* __restrict__ eo16, float* __restrict__ wV, float* __restrict__ z)
{
    __shared__ char smem[49152];
    short* ldsA = (short*)smem;
    short* ldsB = (short*)(smem + 16384);
    const int tid = threadIdx.x;
    const int w = tid >> 6, l = tid & 63;
    const int quad = l >> 4, n16 = l & 15;
    const int m0 = blockIdx.x * 64;

    f32x4 acc[8];
#pragma unroll
    for (int i = 0; i < 8; ++i) { f32x4 zz = {0.f, 0.f, 0.f, 0.f}; acc[i] = zz; }

#pragma unroll
    for (int ii = 0; ii < 4; ++ii) {
        int rl = (w * 4 + ii) * 4 + quad;
        int g = n16 ^ (rl & 15);
        short8 v = *(const short8*)(ef16 + (size_t)(m0 + rl) * 128 + g * 8);
        *(short8*)(ldsA + rl * 128 + n16 * 8) = v;
    }
#pragma unroll
    for (int jj = 0; jj < 8; ++jj) {
        int nl = (w * 8 + jj) * 4 + quad;
        int g = n16 ^ (nl & 15);
        short8 v = *(const short8*)(WeT + (size_t)nl * 128 + g * 8);
        *(short8*)(ldsB + nl * 128 + n16 * 8) = v;
    }
    __syncthreads();
#pragma unroll
    for (int kk = 0; kk < 4; ++kk) {
        int gi = kk * 4 + quad;
        short8 a = *(const short8*)(ldsA + (w * 16 + n16) * 128 + (gi ^ n16) * 8);
#pragma unroll
        for (int ct = 0; ct < 8; ++ct) {
            short8 b = *(const short8*)(ldsB + (ct * 16 + n16) * 128 + (gi ^ n16) * 8);
            acc[ct] = __builtin_amdgcn_mfma_f32_16x16x32_bf16(a, b, acc[ct], 0, 0, 0);
        }
    }

#pragma unroll
    for (int r = 0; r < 4; ++r) {
        int e = m0 + w * 16 + quad * 4 + r;
        int si = srcI[e], di = dstI[e];
        size_t sb = (size_t)si * 128, db = (size_t)di * 128;
#pragma unroll
        for (int ct = 0; ct < 8; ++ct) {
            int f = ct * 16 + n16;
            float sc = bf2f(K16[sb + f]) * bf2f(Q16[db + f]) * 0.25f * acc[ct][r];
            eo16[(size_t)e * 128 + f] = f2bf(sc);
            float hs = sc;
            hs += __shfl_xor(hs, 1); hs += __shfl_xor(hs, 2);
            hs += __shfl_xor(hs, 4); hs += __shfl_xor(hs, 8);
            float s = __expf(fminf(fmaxf(hs, -5.f), 5.f));
            atomicAdd(&wV[db + f], bf2f(V16[sb + f]) * s);
            if (n16 == 0) atomicAdd(&z[(size_t)di * 8 + ct], s);
        }
    }
}

// softmax over 500 valid cols of lp[row][512], write fp32 (ld 500) + bf16 (ld 512, pad 0)
__global__ __launch_bounds__(256) void softmax_k(
    const float* __restrict__ lp, float* __restrict__ outF, short* __restrict__ lg16)
{
    const int tid = threadIdx.x;
    const int w = tid >> 6, l = tid & 63;
    const int row = blockIdx.x * 4 + w;
    const float scale = 0.088388347648318447f;  // 1/sqrt(128)
    float x[8];
#pragma unroll
    for (int j = 0; j < 8; ++j) {
        int c = l + 64 * j;
        x[j] = (c < 500) ? lp[(size_t)row * 512 + c] * scale : -1e30f;
    }
    float m = x[0];
#pragma unroll
    for (int j = 1; j < 8; ++j) m = fmaxf(m, x[j]);
#pragma unroll
    for (int k = 1; k < 64; k <<= 1) m = fmaxf(m, __shfl_xor(m, k));
    float e[8]; float s = 0.f;
#pragma unroll
    for (int j = 0; j < 8; ++j) { int c = l + 64 * j; e[j] = (c < 500) ? __expf(x[j] - m) : 0.f; s += e[j]; }
#pragma unroll
    for (int k = 1; k < 64; k <<= 1) s += __shfl_xor(s, k);
    float inv = 1.f / s;
#pragma unroll
    for (int j = 0; j < 8; ++j) {
        int c = l + 64 * j;
        float pv = e[j] * inv;
        lg16[(size_t)row * 512 + c] = f2bf(pv);
        if (c < 500) outF[(size_t)row * 500 + c] = pv;
    }
}

__global__ void f2b4_k(const float* __restrict__ in, short* __restrict__ out, int n4) {
    int i = blockIdx.x * 256 + threadIdx.x;
    if (i < n4) {
        f32x4 v = ((const f32x4*)in)[i];
        short4v o = { f2bf(v.x), f2bf(v.y), f2bf(v.z), f2bf(v.w) };
        ((short4v*)out)[i] = o;
    }
}

// h_att = wV / (z + 1e-6) -> bf16 (vec4 over [N,128]; 4 consecutive f share a head)
__global__ void hatt_k(const float* __restrict__ wV, const float* __restrict__ z,
                       short* __restrict__ o16, int n4) {
    int i = blockIdx.x * 256 + threadIdx.x;
    if (i < n4) {
        int row = i >> 5, f0 = (i & 31) * 4, h = f0 >> 4;
        float zz = z[row * 8 + h] + 1e-6f;
        f32x4 v = ((const f32x4*)wV)[i];
        short4v o = { f2bf(v.x / zz), f2bf(v.y / zz), f2bf(v.z / zz), f2bf(v.w / zz) };
        ((short4v*)o16)[i] = o;
    }
}

struct PrepArgs { const float* s[14]; short* d[14]; int K[14]; int N[14]; };
// convert weights fp32 [K][N] -> bf16 transposed [N][K]
__global__ void prep_w_k(PrepArgs a) {
    int m = blockIdx.y;
    int K = a.K[m], N = a.N[m];
    int i = blockIdx.x * 256 + threadIdx.x;
    if (i < K * N) {
        int k = i / N, n = i - k * N;
        a.d[m][n * K + k] = f2bf(a.s[m][i]);
    }
}

// k = word_feats@ca_k -> k16[512][128] (rows>=500 zero); v -> vT16[128][512] transposed (cols>=500 zero)
__global__ void ca_kv_k(const float* __restrict__ wf, const float* __restrict__ cak,
                        const float* __restrict__ cav, short* __restrict__ k16, short* __restrict__ vT16) {
    int kw = blockIdx.x, n = threadIdx.x;
    if (kw >= 500) { k16[kw * 128 + n] = 0; vT16[n * 512 + kw] = 0; return; }
    float ak = 0.f, av = 0.f;
    for (int t = 0; t < 300; ++t) {
        float wv = wf[kw * 300 + t];
        ak += wv * cak[t * 128 + n];
        av += wv * cav[t * 128 + n];
    }
    k16[kw * 128 + n] = f2bf(ak);
    vT16[n * 512 + kw] = f2bf(av);
}

extern "C" void kernel_launch(void* const* d_in, const int* in_sizes, int n_in,
                              void* d_out, int out_size, void* d_ws, size_t ws_size,
                              hipStream_t stream)
{
    const int N = 30000, E = 480000;
    const float* node_feats = (const float*)d_in[0];
    const float* edge_feats = (const float*)d_in[1];
    const float* word_feats = (const float*)d_in[2];
    const int*   srcI = (const int*)d_in[3];
    const int*   dstI = (const int*)d_in[4];
    const float* Wq = (const float*)d_in[5];
    const float* Wk = (const float*)d_in[6];
    const float* Wv = (const float*)d_in[7];
    const float* We = (const float*)d_in[8];
    const float* Oh_w = (const float*)d_in[9];
    const float* Oh_b = (const float*)d_in[10];
    const float* Oe_w = (const float*)d_in[11];
    const float* Oe_b = (const float*)d_in[12];
    const float* ln1h_g = (const float*)d_in[13];
    const float* ln1h_b = (const float*)d_in[14];
    const float* ln1e_g = (const float*)d_in[15];
    const float* ln1e_b = (const float*)d_in[16];
    const float* Fh1_w = (const float*)d_in[17];
    const float* Fh1_b = (const float*)d_in[18];
    const float* Fh2_w = (const float*)d_in[19];
    const float* Fh2_b = (const float*)d_in[20];
    const float* Fe1_w = (const float*)d_in[21];
    const float* Fe1_b = (const float*)d_in[22];
    const float* Fe2_w = (const float*)d_in[23];
    const float* Fe2_b = (const float*)d_in[24];
    const float* ln2h_g = (const float*)d_in[25];
    const float* ln2h_b = (const float*)d_in[26];
    const float* ln2e_g = (const float*)d_in[27];
    const float* ln2e_b = (const float*)d_in[28];
    const float* ca_q = (const float*)d_in[29];
    const float* ca_k = (const float*)d_in[30];
    const float* ca_v = (const float*)d_in[31];
    const float* ca_att = (const float*)d_in[32];
    const float* ca_ln1_g = (const float*)d_in[33];
    const float* ca_ln1_b = (const float*)d_in[34];
    const float* ca_ln2_g = (const float*)d_in[35];
    const float* ca_ln2_b = (const float*)d_in[36];
    const float* ca_f1 = (const float*)d_in[37];
    const float* ca_f2 = (const float*)d_in[38];

    float* outLogits = (float*)d_out;                    // [30000][500]
    float* outNf = (float*)d_out + 15000000;             // [30000][128]
    float* outEf = (float*)d_out + 18840000;             // [480000][128]

    char* ws = (char*)d_ws;
    size_t off = 0;
    auto alloc = [&](size_t b) -> char* { size_t o = off; off += (b + 255) & ~(size_t)255; return ws + o; };

    short* nf16   = (short*)alloc((size_t)N * 128 * 2);
    short* ef16   = (short*)alloc((size_t)E * 128 * 2);
    short* WqT    = (short*)alloc(16384 * 2);
    short* WkT    = (short*)alloc(16384 * 2);
    short* WvT    = (short*)alloc(16384 * 2);
    short* WeT    = (short*)alloc(16384 * 2);
    short* OhT    = (short*)alloc(16384 * 2);
    short* OeT    = (short*)alloc(16384 * 2);
    short* caqT   = (short*)alloc(16384 * 2);
    short* caattT = (short*)alloc(16384 * 2);
    short* Fh1T   = (short*)alloc(32768 * 2);
    short* Fe1T   = (short*)alloc(32768 * 2);
    short* caf1T  = (short*)alloc(32768 * 2);
    short* Fh2T   = (short*)alloc(32768 * 2);
    short* Fe2T   = (short*)alloc(32768 * 2);
    short* caf2T  = (short*)alloc(32768 * 2);
    short* k16    = (short*)alloc(512 * 128 * 2);
    short* vT16   = (short*)alloc(128 * 512 * 2);
    short* Q16    = (short*)alloc((size_t)N * 128 * 2);
    short* Kt16   = (short*)alloc((size_t)N * 128 * 2);
    short* V16    = (short*)alloc((size_t)N * 128 * 2);
    float* wV     = (float*)alloc((size_t)N * 128 * 4);
    float* zacc   = (float*)alloc((size_t)N * 8 * 4);    // contiguous after wV
    short* hatt16 = (short*)alloc((size_t)N * 128 * 2);
    short* hf1_16 = (short*)alloc((size_t)N * 128 * 2);
    short* hf2_16 = (short*)alloc((size_t)N * 128 * 2);
    short* q16    = (short*)alloc((size_t)N * 128 * 2);
    short* attv16 = (short*)alloc((size_t)N * 128 * 2);
    short* nf1_16 = (short*)alloc((size_t)N * 128 * 2);
    short* Hc16   = (short*)alloc((size_t)N * 256 * 2);
    short* Hh16   = (short*)alloc((size_t)N * 256 * 2);
    char*  R1     = alloc((size_t)E * 128 * 2);          // e_out16, later lp+lg16
    short* eo16   = (short*)R1;
    float* lp     = (float*)R1;                          // [30000][512] fp32 (after eo16 dead)
    short* lg16   = (short*)(R1 + 61440000);             // [30000][512] bf16
    short* ef1_16 = (short*)alloc((size_t)E * 128 * 2);
    short* He16   = (short*)outEf;                       // FFN hidden [E][256] bf16 inside d_out ef region

    // zero wV+z (contiguous region)
    hipMemsetAsync(wV, 0, (size_t)N * 128 * 4 + (((size_t)N * 8 * 4 + 255) & ~(size_t)255), stream);

    // convert activations to bf16
    f2b4_k<<<dim3((N * 128 / 4 + 255) / 256), 256, 0, stream>>>(node_feats, nf16, N * 128 / 4);
    f2b4_k<<<dim3((E * 128 / 4 + 255) / 256), 256, 0, stream>>>(edge_feats, ef16, E * 128 / 4);

    // prep weights (transpose + bf16)
    PrepArgs pa;
    const float* srcs[14] = {Wq, Wk, Wv, We, Oh_w, Oe_w, ca_q, ca_att, Fh1_w, Fe1_w, ca_f1, Fh2_w, Fe2_w, ca_f2};
    short* dsts[14] = {WqT, WkT, WvT, WeT, OhT, OeT, caqT, caattT, Fh1T, Fe1T, caf1T, Fh2T, Fe2T, caf2T};
    int Ks[14] = {128,128,128,128,128,128,128,128, 128,128,128, 256,256,256};
    int Ns[14] = {128,128,128,128,128,128,128,128, 256,256,256, 128,128,128};
    for (int i = 0; i < 14; ++i) { pa.s[i] = srcs[i]; pa.d[i] = dsts[i]; pa.K[i] = Ks[i]; pa.N[i] = Ns[i]; }
    prep_w_k<<<dim3(128, 14), 256, 0, stream>>>(pa);

    ca_kv_k<<<dim3(512), 128, 0, stream>>>(word_feats, ca_k, ca_v, k16, vT16);

    const int NB = (N + 63) / 64;   // 469
    const int EB = E / 64;          // 7500

    // Q,K,V = nf @ W  -> bf16
    gemm_epi<false,false,false,false,false,true><<<dim3(NB,1),256,0,stream>>>(nf16, WqT, N, 128, nullptr, nullptr, nullptr, nullptr, nullptr, 0, Q16, 128);
    gemm_epi<false,false,false,false,false,true><<<dim3(NB,1),256,0,stream>>>(nf16, WkT, N, 128, nullptr, nullptr, nullptr, nullptr, nullptr, 0, Kt16, 128);
    gemm_epi<false,false,false,false,false,true><<<dim3(NB,1),256,0,stream>>>(nf16, WvT, N, 128, nullptr, nullptr, nullptr, nullptr, nullptr, 0, V16, 128);

    // edge scores + segment sums
    edge_score_k<<<dim3(EB),256,0,stream>>>(ef16, WeT, Q16, Kt16, V16, srcI, dstI, eo16, wV, zacc);

    // ef1 = LN(edge + e_out@Oe + b)
    gemm_epi<true,false,true,true,false,true><<<dim3(EB,1),256,0,stream>>>(eo16, OeT, E, 128, Oe_b, ef16, ln1e_g, ln1e_b, nullptr, 0, ef1_16, 128);
    // He = relu(ef1@Fe1 + b)   (hidden lives in d_out ef region)
    gemm_epi<true,true,false,false,false,true><<<dim3(EB,2),256,0,stream>>>(ef1_16, Fe1T, E, 128, Fe1_b, nullptr, nullptr, nullptr, nullptr, 0, He16, 256);
    // ef = LN(ef1 + He@Fe2 + b) -> d_out (reads He rows before overwriting same bytes; block-private rows)
    gemm_epi<true,false,true,true,true,false><<<dim3(EB,1),256,0,stream>>>(He16, Fe2T, E, 256, Fe2_b, ef1_16, ln2e_g, ln2e_b, outEf, 128, nullptr, 0);

    // node side
    hatt_k<<<dim3((N * 128 / 4 + 255) / 256), 256, 0, stream>>>(wV, zacc, hatt16, N * 128 / 4);
    gemm_epi<true,false,true,true,false,true><<<dim3(NB,1),256,0,stream>>>(hatt16, OhT, N, 128, Oh_b, nf16, ln1h_g, ln1h_b, nullptr, 0, hf1_16, 128);
    gemm_epi<true,true,false,false,false,true><<<dim3(NB,2),256,0,stream>>>(hf1_16, Fh1T, N, 128, Fh1_b, nullptr, nullptr, nullptr, nullptr, 0, Hh16, 256);
    gemm_epi<true,false,true,true,false,true><<<dim3(NB,1),256,0,stream>>>(Hh16, Fh2T, N, 256, Fh2_b, hf1_16, ln2h_g, ln2h_b, nullptr, 0, hf2_16, 128);

    // cross-attention
    gemm_epi<false,false,false,false,false,true><<<dim3(NB,1),256,0,stream>>>(hf2_16, caqT, N, 128, nullptr, nullptr, nullptr, nullptr, nullptr, 0, q16, 128);
    gemm_epi<false,false,false,false,true,false><<<dim3(NB,4),256,0,stream>>>(q16, k16, N, 128, nullptr, nullptr, nullptr, nullptr, lp, 512, nullptr, 0);
    softmax_k<<<dim3(N / 4), 256, 0, stream>>>(lp, outLogits, lg16);
    gemm_epi<false,false,false,false,false,true><<<dim3(NB,1),256,0,stream>>>(lg16, vT16, N, 512, nullptr, nullptr, nullptr, nullptr, nullptr, 0, attv16, 128);
    gemm_epi<false,false,true,true,false,true><<<dim3(NB,1),256,0,stream>>>(attv16, caattT, N, 128, nullptr, hf2_16, ca_ln1_g, ca_ln1_b, nullptr, 0, nf1_16, 128);
    gemm_epi<false,true,false,false,false,true><<<dim3(NB,2),256,0,stream>>>(nf1_16, caf1T, N, 128, nullptr, nullptr, nullptr, nullptr, nullptr, 0, Hc16, 256);
    gemm_epi<false,false,true,true,true,false><<<dim3(NB,1),256,0,stream>>>(Hc16, caf2T, N, 256, nullptr, nf1_16, ca_ln2_g, ca_ln2_b, outNf, 128, nullptr, 0);
}

// Round 3
// 1556.513 us; speedup vs baseline: 1.0440x; 1.0440x over previous
//
#include <hip/hip_runtime.h>
#include <stdint.h>

#define DEVI __device__ __forceinline__

typedef __attribute__((ext_vector_type(8))) short short8;
typedef __attribute__((ext_vector_type(4))) short short4v;
typedef __attribute__((ext_vector_type(4))) float f32x4;

DEVI float bf2f(short s) { union { float f; uint32_t u; } x; x.u = ((uint32_t)(uint16_t)s) << 16; return x.f; }
DEVI short f2bf(float f) { union { float f; uint32_t u; } x; x.f = f; uint32_t r = x.u + 0x7fffu + ((x.u >> 16) & 1u); return (short)(r >> 16); }

// ---------------------------------------------------------------------------
// Generic 64x128-tile bf16 MFMA GEMM: out = epi(A[M,K] @ Bt[N,K]^T)
// A row-major [M][K] bf16; Bt is transposed weights [N][K] bf16.
// Tile: 64 rows x 128 cols per block; 4 waves, wave w owns rows w*16..w*16+15.
// LDS granule XOR swizzle (g ^= row&15) keeps ds_read_b128 frag fetches 2-way.
// Epilogues: bias / relu / residual+LN(128) / fp32 and-or bf16 stores.
// ---------------------------------------------------------------------------
template<bool HB, bool RELU, bool LN, bool RES, bool OF, bool OB>
__global__ __launch_bounds__(256) void gemm_epi(
    const short* __restrict__ A, const short* __restrict__ Bt,
    int M, int K,
    const float* __restrict__ bias,
    const short* __restrict__ res16,
    const float* __restrict__ gamma, const float* __restrict__ beta,
    float* __restrict__ outF, int ldF,
    short* __restrict__ out16, int ld16)
{
    __shared__ char smem[49152];
    short* ldsA = (short*)smem;            // [64][128] shorts, swizzled granules
    short* ldsB = (short*)(smem + 16384);  // [128][128]
    float* ldsE = (float*)smem;            // epilogue [64][132]

    const int tid = threadIdx.x;
    const int w = tid >> 6, l = tid & 63;
    const int quad = l >> 4, n16 = l & 15;
    const int m0 = blockIdx.x * 64;
    const int n0 = blockIdx.y * 128;

    f32x4 acc[8];
#pragma unroll
    for (int i = 0; i < 8; ++i) { f32x4 zz = {0.f, 0.f, 0.f, 0.f}; acc[i] = zz; }

    const int nch = K >> 7;
    for (int c = 0; c < nch; ++c) {
#pragma unroll
        for (int ii = 0; ii < 4; ++ii) {
            int rl = (w * 4 + ii) * 4 + quad;
            int row = m0 + rl; if (row >= M) row = M - 1;
            int g = n16 ^ (rl & 15);
            short8 v = *(const short8*)(A + (size_t)row * K + c * 128 + g * 8);
            *(short8*)(ldsA + rl * 128 + n16 * 8) = v;
        }
#pragma unroll
        for (int jj = 0; jj < 8; ++jj) {
            int nl = (w * 8 + jj) * 4 + quad;
            int g = n16 ^ (nl & 15);
            short8 v = *(const short8*)(Bt + (size_t)(n0 + nl) * K + c * 128 + g * 8);
            *(short8*)(ldsB + nl * 128 + n16 * 8) = v;
        }
        __syncthreads();
#pragma unroll
        for (int kk = 0; kk < 4; ++kk) {
            int gi = kk * 4 + quad;
            short8 a = *(const short8*)(ldsA + (w * 16 + n16) * 128 + (gi ^ n16) * 8);
#pragma unroll
            for (int ct = 0; ct < 8; ++ct) {
                short8 b = *(const short8*)(ldsB + (ct * 16 + n16) * 128 + (gi ^ n16) * 8);
                acc[ct] = __builtin_amdgcn_mfma_f32_16x16x32_bf16(a, b, acc[ct], 0, 0, 0);
            }
        }
        __syncthreads();
    }

    // stage C tile to LDS (fp32, padded stride 132) for row-wise epilogue
#pragma unroll
    for (int ct = 0; ct < 8; ++ct)
#pragma unroll
        for (int r = 0; r < 4; ++r)
            ldsE[(w * 16 + quad * 4 + r) * 132 + ct * 16 + n16] = acc[ct][r];
    __syncthreads();

    const int rl = tid >> 2, p = tid & 3;
    const int row = m0 + rl;
    const bool valid = row < M;
    const int cb = p * 32;
    float v[32];
#pragma unroll
    for (int j = 0; j < 32; ++j) v[j] = ldsE[rl * 132 + cb + j];
    if (HB) {
#pragma unroll
        for (int j = 0; j < 32; ++j) v[j] += bias[n0 + cb + j];
    }
    if (RES) {
        if (valid) {
#pragma unroll
            for (int j = 0; j < 32; ++j) v[j] += bf2f(res16[(size_t)row * 128 + cb + j]);
        }
    }
    if (RELU) {
#pragma unroll
        for (int j = 0; j < 32; ++j) v[j] = fmaxf(v[j], 0.f);
    }
    if (LN) {  // N==128 required: full row in block
        float s = 0.f, q = 0.f;
#pragma unroll
        for (int j = 0; j < 32; ++j) { s += v[j]; q += v[j] * v[j]; }
        s += __shfl_xor(s, 1); q += __shfl_xor(q, 1);
        s += __shfl_xor(s, 2); q += __shfl_xor(q, 2);
        float mean = s * (1.f / 128.f);
        float var = q * (1.f / 128.f) - mean * mean;
        float inv = rsqrtf(var + 1e-5f);
#pragma unroll
        for (int j = 0; j < 32; ++j) v[j] = (v[j] - mean) * inv * gamma[cb + j] + beta[cb + j];
    }
    if (valid) {
        if (OF) {
#pragma unroll
            for (int jj = 0; jj < 8; ++jj) {
                f32x4 t = { v[jj*4], v[jj*4+1], v[jj*4+2], v[jj*4+3] };
                *(f32x4*)(outF + (size_t)row * ldF + n0 + cb + jj * 4) = t;
            }
        }
        if (OB) {
#pragma unroll
            for (int jj = 0; jj < 8; ++jj) {
                short4v t = { f2bf(v[jj*4]), f2bf(v[jj*4+1]), f2bf(v[jj*4+2]), f2bf(v[jj*4+3]) };
                *(short4v*)(out16 + (size_t)row * ld16 + n0 + cb + jj * 4) = t;
            }
        }
    }
}

// ---------------------------------------------------------------------------
// Edge kernel: pe = ef16 @ WeT (MFMA), then per-edge
//   score = K[src]*Q[dst]*0.25*pe  -> e_out (bf16)
//   s = exp(clip(sum_d score, -5, 5)) per head -> sE[e][8]  (no atomics)
// LDS: ldsA 16KB + ldsB 32KB = 48KB (DO NOT SHRINK — ldsB spans [128][128])
// ---------------------------------------------------------------------------
__global__ __launch_bounds__(256) void edge_score_k(
    const short* __restrict__ ef16, const short* __restrict__ WeT,
    const short* __restrict__ Q16, const short* __restrict__ K16,
    const int* __restrict__ srcI, const int* __restrict__ dstI,
    short* __restrict__ eo16, float* __restrict__ sE)
{
    __shared__ char smem[49152];
    short* ldsA = (short*)smem;
    short* ldsB = (short*)(smem + 16384);
    const int tid = threadIdx.x;
    const int w = tid >> 6, l = tid & 63;
    const int quad = l >> 4, n16 = l & 15;
    const int m0 = blockIdx.x * 64;

    f32x4 acc[8];
#pragma unroll
    for (int i = 0; i < 8; ++i) { f32x4 zz = {0.f, 0.f, 0.f, 0.f}; acc[i] = zz; }

#pragma unroll
    for (int ii = 0; ii < 4; ++ii) {
        int rl = (w * 4 + ii) * 4 + quad;
        int g = n16 ^ (rl & 15);
        short8 v = *(const short8*)(ef16 + (size_t)(m0 + rl) * 128 + g * 8);
        *(short8*)(ldsA + rl * 128 + n16 * 8) = v;
    }
#pragma unroll
    for (int jj = 0; jj < 8; ++jj) {
        int nl = (w * 8 + jj) * 4 + quad;
        int g = n16 ^ (nl & 15);
        short8 v = *(const short8*)(WeT + (size_t)nl * 128 + g * 8);
        *(short8*)(ldsB + nl * 128 + n16 * 8) = v;
    }
    __syncthreads();
#pragma unroll
    for (int kk = 0; kk < 4; ++kk) {
        int gi = kk * 4 + quad;
        short8 a = *(const short8*)(ldsA + (w * 16 + n16) * 128 + (gi ^ n16) * 8);
#pragma unroll
        for (int ct = 0; ct < 8; ++ct) {
            short8 b = *(const short8*)(ldsB + (ct * 16 + n16) * 128 + (gi ^ n16) * 8);
            acc[ct] = __builtin_amdgcn_mfma_f32_16x16x32_bf16(a, b, acc[ct], 0, 0, 0);
        }
    }

#pragma unroll
    for (int r = 0; r < 4; ++r) {
        int e = m0 + w * 16 + quad * 4 + r;
        int si = srcI[e], di = dstI[e];
        size_t sb = (size_t)si * 128, db = (size_t)di * 128;
#pragma unroll
        for (int ct = 0; ct < 8; ++ct) {
            int f = ct * 16 + n16;
            float sc = bf2f(K16[sb + f]) * bf2f(Q16[db + f]) * 0.25f * acc[ct][r];
            eo16[(size_t)e * 128 + f] = f2bf(sc);
            float hs = sc;
            hs += __shfl_xor(hs, 1); hs += __shfl_xor(hs, 2);
            hs += __shfl_xor(hs, 4); hs += __shfl_xor(hs, 8);
            if (n16 == 0) {
                float s = __expf(fminf(fmaxf(hs, -5.f), 5.f));
                sE[(size_t)e * 8 + ct] = s;
            }
        }
    }
}

// -------------------- dst-CSR build (replaces wV/z atomics) -----------------
__global__ void hist_k(const int* __restrict__ dst, int* __restrict__ cnt, int n) {
    int i = blockIdx.x * 256 + threadIdx.x;
    if (i < n) atomicAdd(&cnt[dst[i]], 1);
}

// single-block exclusive scan over 30000 bins -> rowptr[30001] and cursor copy
__global__ __launch_bounds__(1024) void scan_k(
    const int* __restrict__ cnt, int* __restrict__ rowptr, int* __restrict__ cursor)
{
    __shared__ int part[1024];
    const int NBINS = 30000, PER = 30;
    int t = threadIdx.x;
    int base = t * PER;
    int s = 0;
    for (int j = 0; j < PER; ++j) {
        int b = base + j;
        s += (b < NBINS) ? cnt[b] : 0;
    }
    part[t] = s;
    __syncthreads();
    for (int off = 1; off < 1024; off <<= 1) {
        int x = (t >= off) ? part[t - off] : 0;
        __syncthreads();
        part[t] += x;
        __syncthreads();
    }
    int run = part[t] - s;  // exclusive prefix of this thread's chunk
    for (int j = 0; j < PER; ++j) {
        int b = base + j;
        if (b < NBINS) {
            rowptr[b] = run; cursor[b] = run;
            run += cnt[b];
        }
    }
    if (t == 1023) rowptr[NBINS] = part[1023];
}

__global__ void scatter_k(const int* __restrict__ dst, int* __restrict__ cursor,
                          int* __restrict__ eid, int n) {
    int i = blockIdx.x * 256 + threadIdx.x;
    if (i < n) { int p = atomicAdd(&cursor[dst[i]], 1); eid[p] = i; }
}

// h_att[n] = sum_{e in CSR(n)} V[src(e)]*s[e][h] / (sum s + 1e-6)  -> bf16
// one wave per dst node; lane l owns features l and l+64 (head = f>>4)
__global__ __launch_bounds__(256) void gather_k(
    const int* __restrict__ rowptr, const int* __restrict__ eid,
    const int* __restrict__ srcI, const float* __restrict__ sE,
    const short* __restrict__ V16, short* __restrict__ hatt)
{
    const int w = threadIdx.x >> 6, l = threadIdx.x & 63;
    const int n = blockIdx.x * 4 + w;
    if (n >= 30000) return;
    const int beg = rowptr[n], end = rowptr[n + 1];
    const int h = l >> 4;
    float a0 = 0.f, a1 = 0.f, z0 = 0.f, z1 = 0.f;
    for (int i = beg; i < end; ++i) {
        int e = eid[i];
        int si = srcI[e];
        float s0 = sE[(size_t)e * 8 + h];
        float s1 = sE[(size_t)e * 8 + 4 + h];
        float v0 = bf2f(V16[(size_t)si * 128 + l]);
        float v1 = bf2f(V16[(size_t)si * 128 + 64 + l]);
        a0 += v0 * s0; a1 += v1 * s1; z0 += s0; z1 += s1;
    }
    hatt[(size_t)n * 128 + l]      = f2bf(a0 / (z0 + 1e-6f));
    hatt[(size_t)n * 128 + 64 + l] = f2bf(a1 / (z1 + 1e-6f));
}

// softmax over 500 valid cols of lp[row][512], write fp32 (ld 500) + bf16 (ld 512, pad 0)
__global__ __launch_bounds__(256) void softmax_k(
    const float* __restrict__ lp, float* __restrict__ outF, short* __restrict__ lg16)
{
    const int tid = threadIdx.x;
    const int w = tid >> 6, l = tid & 63;
    const int row = blockIdx.x * 4 + w;
    const float scale = 0.088388347648318447f;  // 1/sqrt(128)
    float x[8];
#pragma unroll
    for (int j = 0; j < 8; ++j) {
        int c = l + 64 * j;
        x[j] = (c < 500) ? lp[(size_t)row * 512 + c] * scale : -1e30f;
    }
    float m = x[0];
#pragma unroll
    for (int j = 1; j < 8; ++j) m = fmaxf(m, x[j]);
#pragma unroll
    for (int k = 1; k < 64; k <<= 1) m = fmaxf(m, __shfl_xor(m, k));
    float e[8]; float s = 0.f;
#pragma unroll
    for (int j = 0; j < 8; ++j) { int c = l + 64 * j; e[j] = (c < 500) ? __expf(x[j] - m) : 0.f; s += e[j]; }
#pragma unroll
    for (int k = 1; k < 64; k <<= 1) s += __shfl_xor(s, k);
    float inv = 1.f / s;
#pragma unroll
    for (int j = 0; j < 8; ++j) {
        int c = l + 64 * j;
        float pv = e[j] * inv;
        lg16[(size_t)row * 512 + c] = f2bf(pv);
        if (c < 500) outF[(size_t)row * 500 + c] = pv;
    }
}

__global__ void f2b4_k(const float* __restrict__ in, short* __restrict__ out, int n4) {
    int i = blockIdx.x * 256 + threadIdx.x;
    if (i < n4) {
        f32x4 v = ((const f32x4*)in)[i];
        short4v o = { f2bf(v.x), f2bf(v.y), f2bf(v.z), f2bf(v.w) };
        ((short4v*)out)[i] = o;
    }
}

struct PrepArgs { const float* s[14]; short* d[14]; int K[14]; int N[14]; };
// convert weights fp32 [K][N] -> bf16 transposed [N][K]
__global__ void prep_w_k(PrepArgs a) {
    int m = blockIdx.y;
    int K = a.K[m], N = a.N[m];
    int i = blockIdx.x * 256 + threadIdx.x;
    if (i < K * N) {
        int k = i / N, n = i - k * N;
        a.d[m][n * K + k] = f2bf(a.s[m][i]);
    }
}

// k = word_feats@ca_k -> k16[512][128] (rows>=500 zero); v -> vT16[128][512] transposed (cols>=500 zero)
__global__ void ca_kv_k(const float* __restrict__ wf, const float* __restrict__ cak,
                        const float* __restrict__ cav, short* __restrict__ k16, short* __restrict__ vT16) {
    int kw = blockIdx.x, n = threadIdx.x;
    if (kw >= 500) { k16[kw * 128 + n] = 0; vT16[n * 512 + kw] = 0; return; }
    float ak = 0.f, av = 0.f;
    for (int t = 0; t < 300; ++t) {
        float wv = wf[kw * 300 + t];
        ak += wv * cak[t * 128 + n];
        av += wv * cav[t * 128 + n];
    }
    k16[kw * 128 + n] = f2bf(ak);
    vT16[n * 512 + kw] = f2bf(av);
}

extern "C" void kernel_launch(void* const* d_in, const int* in_sizes, int n_in,
                              void* d_out, int out_size, void* d_ws, size_t ws_size,
                              hipStream_t stream)
{
    const int N = 30000, E = 480000;
    const float* node_feats = (const float*)d_in[0];
    const float* edge_feats = (const float*)d_in[1];
    const float* word_feats = (const float*)d_in[2];
    const int*   srcI = (const int*)d_in[3];
    const int*   dstI = (const int*)d_in[4];
    const float* Wq = (const float*)d_in[5];
    const float* Wk = (const float*)d_in[6];
    const float* Wv = (const float*)d_in[7];
    const float* We = (const float*)d_in[8];
    const float* Oh_w = (const float*)d_in[9];
    const float* Oh_b = (const float*)d_in[10];
    const float* Oe_w = (const float*)d_in[11];
    const float* Oe_b = (const float*)d_in[12];
    const float* ln1h_g = (const float*)d_in[13];
    const float* ln1h_b = (const float*)d_in[14];
    const float* ln1e_g = (const float*)d_in[15];
    const float* ln1e_b = (const float*)d_in[16];
    const float* Fh1_w = (const float*)d_in[17];
    const float* Fh1_b = (const float*)d_in[18];
    const float* Fh2_w = (const float*)d_in[19];
    const float* Fh2_b = (const float*)d_in[20];
    const float* Fe1_w = (const float*)d_in[21];
    const float* Fe1_b = (const float*)d_in[22];
    const float* Fe2_w = (const float*)d_in[23];
    const float* Fe2_b = (const float*)d_in[24];
    const float* ln2h_g = (const float*)d_in[25];
    const float* ln2h_b = (const float*)d_in[26];
    const float* ln2e_g = (const float*)d_in[27];
    const float* ln2e_b = (const float*)d_in[28];
    const float* ca_q = (const float*)d_in[29];
    const float* ca_k = (const float*)d_in[30];
    const float* ca_v = (const float*)d_in[31];
    const float* ca_att = (const float*)d_in[32];
    const float* ca_ln1_g = (const float*)d_in[33];
    const float* ca_ln1_b = (const float*)d_in[34];
    const float* ca_ln2_g = (const float*)d_in[35];
    const float* ca_ln2_b = (const float*)d_in[36];
    const float* ca_f1 = (const float*)d_in[37];
    const float* ca_f2 = (const float*)d_in[38];

    float* outLogits = (float*)d_out;                    // [30000][500]
    float* outNf = (float*)d_out + 15000000;             // [30000][128]
    float* outEf = (float*)d_out + 18840000;             // [480000][128]

    char* ws = (char*)d_ws;
    size_t off = 0;
    auto alloc = [&](size_t b) -> char* { size_t o = off; off += (b + 255) & ~(size_t)255; return ws + o; };

    short* nf16   = (short*)alloc((size_t)N * 128 * 2);
    short* ef16   = (short*)alloc((size_t)E * 128 * 2);
    short* WqT    = (short*)alloc(16384 * 2);
    short* WkT    = (short*)alloc(16384 * 2);
    short* WvT    = (short*)alloc(16384 * 2);
    short* WeT    = (short*)alloc(16384 * 2);
    short* OhT    = (short*)alloc(16384 * 2);
    short* OeT    = (short*)alloc(16384 * 2);
    short* caqT   = (short*)alloc(16384 * 2);
    short* caattT = (short*)alloc(16384 * 2);
    short* Fh1T   = (short*)alloc(32768 * 2);
    short* Fe1T   = (short*)alloc(32768 * 2);
    short* caf1T  = (short*)alloc(32768 * 2);
    short* Fh2T   = (short*)alloc(32768 * 2);
    short* Fe2T   = (short*)alloc(32768 * 2);
    short* caf2T  = (short*)alloc(32768 * 2);
    short* k16    = (short*)alloc(512 * 128 * 2);
    short* vT16   = (short*)alloc(128 * 512 * 2);
    short* Q16    = (short*)alloc((size_t)N * 128 * 2);
    short* Kt16   = (short*)alloc((size_t)N * 128 * 2);
    short* V16    = (short*)alloc((size_t)N * 128 * 2);
    float* sE     = (float*)alloc((size_t)E * 8 * 4);    // per-(edge,head) exp score
    int*   cnt    = (int*)alloc((size_t)N * 4);
    int*   rowptr = (int*)alloc((size_t)(N + 1) * 4);
    int*   cursor = (int*)alloc((size_t)N * 4);
    int*   eid    = (int*)alloc((size_t)E * 4);
    short* hatt16 = (short*)alloc((size_t)N * 128 * 2);
    short* hf1_16 = (short*)alloc((size_t)N * 128 * 2);
    short* hf2_16 = (short*)alloc((size_t)N * 128 * 2);
    short* q16    = (short*)alloc((size_t)N * 128 * 2);
    short* attv16 = (short*)alloc((size_t)N * 128 * 2);
    short* nf1_16 = (short*)alloc((size_t)N * 128 * 2);
    short* Hc16   = (short*)alloc((size_t)N * 256 * 2);
    short* Hh16   = (short*)alloc((size_t)N * 256 * 2);
    char*  R1     = alloc((size_t)E * 128 * 2);          // e_out16, later lp+lg16
    short* eo16   = (short*)R1;
    float* lp     = (float*)R1;                          // [30000][512] fp32 (after eo16 dead)
    short* lg16   = (short*)(R1 + 61440000);             // [30000][512] bf16
    short* ef1_16 = (short*)alloc((size_t)E * 128 * 2);
    short* He16   = (short*)outEf;                       // FFN hidden [E][256] bf16 inside d_out ef region

    // zero dst histogram
    hipMemsetAsync(cnt, 0, (size_t)N * 4, stream);

    // convert activations to bf16
    f2b4_k<<<dim3((N * 128 / 4 + 255) / 256), 256, 0, stream>>>(node_feats, nf16, N * 128 / 4);
    f2b4_k<<<dim3((E * 128 / 4 + 255) / 256), 256, 0, stream>>>(edge_feats, ef16, E * 128 / 4);

    // prep weights (transpose + bf16)
    PrepArgs pa;
    const float* srcs[14] = {Wq, Wk, Wv, We, Oh_w, Oe_w, ca_q, ca_att, Fh1_w, Fe1_w, ca_f1, Fh2_w, Fe2_w, ca_f2};
    short* dsts[14] = {WqT, WkT, WvT, WeT, OhT, OeT, caqT, caattT, Fh1T, Fe1T, caf1T, Fh2T, Fe2T, caf2T};
    int Ks[14] = {128,128,128,128,128,128,128,128, 128,128,128, 256,256,256};
    int Ns[14] = {128,128,128,128,128,128,128,128, 256,256,256, 128,128,128};
    for (int i = 0; i < 14; ++i) { pa.s[i] = srcs[i]; pa.d[i] = dsts[i]; pa.K[i] = Ks[i]; pa.N[i] = Ns[i]; }
    prep_w_k<<<dim3(128, 14), 256, 0, stream>>>(pa);

    ca_kv_k<<<dim3(512), 128, 0, stream>>>(word_feats, ca_k, ca_v, k16, vT16);

    // dst-CSR build
    hist_k<<<dim3((E + 255) / 256), 256, 0, stream>>>(dstI, cnt, E);
    scan_k<<<dim3(1), 1024, 0, stream>>>(cnt, rowptr, cursor);
    scatter_k<<<dim3((E + 255) / 256), 256, 0, stream>>>(dstI, cursor, eid, E);

    const int NB = (N + 63) / 64;   // 469
    const int EB = E / 64;          // 7500

    // Q,K,V = nf @ W  -> bf16
    gemm_epi<false,false,false,false,false,true><<<dim3(NB,1),256,0,stream>>>(nf16, WqT, N, 128, nullptr, nullptr, nullptr, nullptr, nullptr, 0, Q16, 128);
    gemm_epi<false,false,false,false,false,true><<<dim3(NB,1),256,0,stream>>>(nf16, WkT, N, 128, nullptr, nullptr, nullptr, nullptr, nullptr, 0, Kt16, 128);
    gemm_epi<false,false,false,false,false,true><<<dim3(NB,1),256,0,stream>>>(nf16, WvT, N, 128, nullptr, nullptr, nullptr, nullptr, nullptr, 0, V16, 128);

    // edge scores (no atomics)
    edge_score_k<<<dim3(EB),256,0,stream>>>(ef16, WeT, Q16, Kt16, srcI, dstI, eo16, sE);

    // h_att via CSR gather
    gather_k<<<dim3((N + 3) / 4), 256, 0, stream>>>(rowptr, eid, srcI, sE, V16, hatt16);

    // ef1 = LN(edge + e_out@Oe + b)
    gemm_epi<true,false,true,true,false,true><<<dim3(EB,1),256,0,stream>>>(eo16, OeT, E, 128, Oe_b, ef16, ln1e_g, ln1e_b, nullptr, 0, ef1_16, 128);
    // He = relu(ef1@Fe1 + b)   (hidden lives in d_out ef region)
    gemm_epi<true,true,false,false,false,true><<<dim3(EB,2),256,0,stream>>>(ef1_16, Fe1T, E, 128, Fe1_b, nullptr, nullptr, nullptr, nullptr, 0, He16, 256);
    // ef = LN(ef1 + He@Fe2 + b) -> d_out (reads He rows before overwriting same bytes; block-private rows)
    gemm_epi<true,false,true,true,true,false><<<dim3(EB,1),256,0,stream>>>(He16, Fe2T, E, 256, Fe2_b, ef1_16, ln2e_g, ln2e_b, outEf, 128, nullptr, 0);

    // node side
    gemm_epi<true,false,true,true,false,true><<<dim3(NB,1),256,0,stream>>>(hatt16, OhT, N, 128, Oh_b, nf16, ln1h_g, ln1h_b, nullptr, 0, hf1_16, 128);
    gemm_epi<true,true,false,false,false,true><<<dim3(NB,2),256,0,stream>>>(hf1_16, Fh1T, N, 128, Fh1_b, nullptr, nullptr, nullptr, nullptr, 0, Hh16, 256);
    gemm_epi<true,false,true,true,false,true><<<dim3(NB,1),256,0,stream>>>(Hh16, Fh2T, N, 256, Fh2_b, hf1_16, ln2h_g, ln2h_b, nullptr, 0, hf2_16, 128);

    // cross-attention
    gemm_epi<false,false,false,false,false,true><<<dim3(NB,1),256,0,stream>>>(hf2_16, caqT, N, 128, nullptr, nullptr, nullptr, nullptr, nullptr, 0, q16, 128);
    gemm_epi<false,false,false,false,true,false><<<dim3(NB,4),256,0,stream>>>(q16, k16, N, 128, nullptr, nullptr, nullptr, nullptr, lp, 512, nullptr, 0);
    softmax_k<<<dim3(N / 4), 256, 0, stream>>>(lp, outLogits, lg16);
    gemm_epi<false,false,false,false,false,true><<<dim3(NB,1),256,0,stream>>>(lg16, vT16, N, 512, nullptr, nullptr, nullptr, nullptr, nullptr, 0, attv16, 128);
    gemm_epi<false,false,true,true,false,true><<<dim3(NB,1),256,0,stream>>>(attv16, caattT, N, 128, nullptr, hf2_16, ca_ln1_g, ca_ln1_b, nullptr, 0, nf1_16, 128);
    gemm_epi<false,true,false,false,false,true><<<dim3(NB,2),256,0,stream>>>(nf1_16, caf1T, N, 128, nullptr, nullptr, nullptr, nullptr, nullptr, 0, Hc16, 256);
    gemm_epi<false,false,true,true,true,false><<<dim3(NB,1),256,0,stream>>>(Hc16, caf2T, N, 256, nullptr, nf1_16, ca_ln2_g, ca_ln2_b, outNf, 128, nullptr, 0);
}

// Round 4
// 1497.648 us; speedup vs baseline: 1.0850x; 1.0393x over previous
//
#include <hip/hip_runtime.h>
#include <stdint.h>

#define DEVI __device__ __forceinline__

typedef __attribute__((ext_vector_type(8))) short short8;
typedef __attribute__((ext_vector_type(4))) short short4v;
typedef __attribute__((ext_vector_type(4))) float f32x4;

DEVI float bf2f(short s) { union { float f; uint32_t u; } x; x.u = ((uint32_t)(uint16_t)s) << 16; return x.f; }
DEVI short f2bf(float f) { union { float f; uint32_t u; } x; x.f = f; uint32_t r = x.u + 0x7fffu + ((x.u >> 16) & 1u); return (short)(r >> 16); }

// ---------------------------------------------------------------------------
// Generic 64x128-tile bf16 MFMA GEMM: out = epi(A[M,K] @ Bt[N,K]^T)
// (used for node-side + cross-attention chains)
// ---------------------------------------------------------------------------
template<bool HB, bool RELU, bool LN, bool RES, bool OF, bool OB>
__global__ __launch_bounds__(256) void gemm_epi(
    const short* __restrict__ A, const short* __restrict__ Bt,
    int M, int K,
    const float* __restrict__ bias,
    const short* __restrict__ res16,
    const float* __restrict__ gamma, const float* __restrict__ beta,
    float* __restrict__ outF, int ldF,
    short* __restrict__ out16, int ld16)
{
    __shared__ char smem[49152];
    short* ldsA = (short*)smem;            // [64][128] shorts, swizzled granules
    short* ldsB = (short*)(smem + 16384);  // [128][128]
    float* ldsE = (float*)smem;            // epilogue [64][132]

    const int tid = threadIdx.x;
    const int w = tid >> 6, l = tid & 63;
    const int quad = l >> 4, n16 = l & 15;
    const int m0 = blockIdx.x * 64;
    const int n0 = blockIdx.y * 128;

    f32x4 acc[8];
#pragma unroll
    for (int i = 0; i < 8; ++i) { f32x4 zz = {0.f, 0.f, 0.f, 0.f}; acc[i] = zz; }

    const int nch = K >> 7;
    for (int c = 0; c < nch; ++c) {
#pragma unroll
        for (int ii = 0; ii < 4; ++ii) {
            int rl = (w * 4 + ii) * 4 + quad;
            int row = m0 + rl; if (row >= M) row = M - 1;
            int g = n16 ^ (rl & 15);
            short8 v = *(const short8*)(A + (size_t)row * K + c * 128 + g * 8);
            *(short8*)(ldsA + rl * 128 + n16 * 8) = v;
        }
#pragma unroll
        for (int jj = 0; jj < 8; ++jj) {
            int nl = (w * 8 + jj) * 4 + quad;
            int g = n16 ^ (nl & 15);
            short8 v = *(const short8*)(Bt + (size_t)(n0 + nl) * K + c * 128 + g * 8);
            *(short8*)(ldsB + nl * 128 + n16 * 8) = v;
        }
        __syncthreads();
#pragma unroll
        for (int kk = 0; kk < 4; ++kk) {
            int gi = kk * 4 + quad;
            short8 a = *(const short8*)(ldsA + (w * 16 + n16) * 128 + (gi ^ n16) * 8);
#pragma unroll
            for (int ct = 0; ct < 8; ++ct) {
                short8 b = *(const short8*)(ldsB + (ct * 16 + n16) * 128 + (gi ^ n16) * 8);
                acc[ct] = __builtin_amdgcn_mfma_f32_16x16x32_bf16(a, b, acc[ct], 0, 0, 0);
            }
        }
        __syncthreads();
    }

    // stage C tile to LDS (fp32, padded stride 132) for row-wise epilogue
#pragma unroll
    for (int ct = 0; ct < 8; ++ct)
#pragma unroll
        for (int r = 0; r < 4; ++r)
            ldsE[(w * 16 + quad * 4 + r) * 132 + ct * 16 + n16] = acc[ct][r];
    __syncthreads();

    const int rl = tid >> 2, p = tid & 3;
    const int row = m0 + rl;
    const bool valid = row < M;
    const int cb = p * 32;
    float v[32];
#pragma unroll
    for (int j = 0; j < 32; ++j) v[j] = ldsE[rl * 132 + cb + j];
    if (HB) {
#pragma unroll
        for (int j = 0; j < 32; ++j) v[j] += bias[n0 + cb + j];
    }
    if (RES) {
        if (valid) {
#pragma unroll
            for (int j = 0; j < 32; ++j) v[j] += bf2f(res16[(size_t)row * 128 + cb + j]);
        }
    }
    if (RELU) {
#pragma unroll
        for (int j = 0; j < 32; ++j) v[j] = fmaxf(v[j], 0.f);
    }
    if (LN) {  // N==128 required: full row in block
        float s = 0.f, q = 0.f;
#pragma unroll
        for (int j = 0; j < 32; ++j) { s += v[j]; q += v[j] * v[j]; }
        s += __shfl_xor(s, 1); q += __shfl_xor(q, 1);
        s += __shfl_xor(s, 2); q += __shfl_xor(q, 2);
        float mean = s * (1.f / 128.f);
        float var = q * (1.f / 128.f) - mean * mean;
        float inv = rsqrtf(var + 1e-5f);
#pragma unroll
        for (int j = 0; j < 32; ++j) v[j] = (v[j] - mean) * inv * gamma[cb + j] + beta[cb + j];
    }
    if (valid) {
        if (OF) {
#pragma unroll
            for (int jj = 0; jj < 8; ++jj) {
                f32x4 t = { v[jj*4], v[jj*4+1], v[jj*4+2], v[jj*4+3] };
                *(f32x4*)(outF + (size_t)row * ldF + n0 + cb + jj * 4) = t;
            }
        }
        if (OB) {
#pragma unroll
            for (int jj = 0; jj < 8; ++jj) {
                short4v t = { f2bf(v[jj*4]), f2bf(v[jj*4+1]), f2bf(v[jj*4+2]), f2bf(v[jj*4+3]) };
                *(short4v*)(out16 + (size_t)row * ld16 + n0 + cb + jj * 4) = t;
            }
        }
    }
}

// ------------------------- fused edge chain helpers -------------------------
DEVI void stage_bw(const short* __restrict__ src, int ldK, short* lds,
                   int w, int quad, int n16) {
#pragma unroll
    for (int jj = 0; jj < 8; ++jj) {
        int nl = (w * 8 + jj) * 4 + quad;
        int g = n16 ^ (nl & 15);
        short8 v = *(const short8*)(src + (size_t)nl * ldK + g * 8);
        *(short8*)(lds + nl * 128 + n16 * 8) = v;
    }
}

DEVI void mfma_tile(const short* ldsA, const short* ldsB, f32x4* acc,
                    int w, int quad, int n16) {
#pragma unroll
    for (int kk = 0; kk < 4; ++kk) {
        int gi = kk * 4 + quad;
        short8 a = *(const short8*)(ldsA + (w * 16 + n16) * 128 + ((gi ^ n16)) * 8);
#pragma unroll
        for (int ct = 0; ct < 8; ++ct) {
            short8 b = *(const short8*)(ldsB + (ct * 16 + n16) * 128 + ((gi ^ n16)) * 8);
            acc[ct] = __builtin_amdgcn_mfma_f32_16x16x32_bf16(a, b, acc[ct], 0, 0, 0);
        }
    }
}

// write C-layout regs as bf16 swizzled A-tile ([64][128], granule g ^= row&15)
DEVI void cwrite_lds(const f32x4* acc, short* lds, int w, int quad, int n16) {
#pragma unroll
    for (int r = 0; r < 4; ++r) {
        int rl = w * 16 + quad * 4 + r;
#pragma unroll
        for (int ct = 0; ct < 8; ++ct) {
            int col = ct * 16 + n16;
            int gp = (col >> 3) ^ (rl & 15);
            lds[rl * 128 + gp * 8 + (col & 7)] = f2bf(acc[ct][r]);
        }
    }
}

DEVI float lds_at(const short* lds, int rl, int col) {
    int gp = (col >> 3) ^ (rl & 15);
    return bf2f(lds[rl * 128 + gp * 8 + (col & 7)]);
}

// ---------------------------------------------------------------------------
// Fused edge chain, one 64-edge tile per block:
//   pe = ef@We ; sc = K[src]*Q[dst]*0.25*pe ; sE = exp(clip(head-sum))
//   ef1 = LN1(ef + sc@Oe + Oe_b)            (in-reg LN via shfl over n16)
//   H   = relu(ef1@Fe1 + b)  (two 128-col halves, LDS-resident)
//   out = LN2(ef1 + H@Fe2 + b) -> outEf fp32
// Never materializes eo/ef1/He in HBM. LDS 64KB: [EF->H 16K][eo->ef1 16K][W 32K]
// ---------------------------------------------------------------------------
__global__ __launch_bounds__(256) void edge_fused_k(
    const float* __restrict__ edge_feats, const short* __restrict__ WeT,
    const short* __restrict__ Q16, const short* __restrict__ K16,
    const int* __restrict__ srcI, const int* __restrict__ dstI,
    const short* __restrict__ OeT, const float* __restrict__ Oe_b,
    const float* __restrict__ ln1e_g, const float* __restrict__ ln1e_b,
    const short* __restrict__ Fe1T, const float* __restrict__ Fe1_b,
    const short* __restrict__ Fe2T, const float* __restrict__ Fe2_b,
    const float* __restrict__ ln2e_g, const float* __restrict__ ln2e_b,
    float* __restrict__ sE, float* __restrict__ outEf)
{
    __shared__ char smem[65536];
    short* ldsEF = (short*)smem;            // ef tile, later H halves
    short* ldsX  = (short*)(smem + 16384);  // eo tile -> ef1 tile
    short* ldsW  = (short*)(smem + 32768);  // weight staging (restaged 6x)

    const int tid = threadIdx.x;
    const int w = tid >> 6, l = tid & 63;
    const int quad = l >> 4, n16 = l & 15;
    const int m0 = blockIdx.x * 64;

    // S0: stage edge_feats fp32 -> bf16 tile, and WeT
#pragma unroll
    for (int ii = 0; ii < 4; ++ii) {
        int rl = (w * 4 + ii) * 4 + quad;
        int g = n16 ^ (rl & 15);
        const float* src = edge_feats + (size_t)(m0 + rl) * 128 + g * 8;
        f32x4 u0 = *(const f32x4*)src;
        f32x4 u1 = *(const f32x4*)(src + 4);
        short8 v = { f2bf(u0.x), f2bf(u0.y), f2bf(u0.z), f2bf(u0.w),
                     f2bf(u1.x), f2bf(u1.y), f2bf(u1.z), f2bf(u1.w) };
        *(short8*)(ldsEF + rl * 128 + n16 * 8) = v;
    }
    stage_bw(WeT, 128, ldsW, w, quad, n16);
    __syncthreads();                                   // A

    f32x4 acc[8];
#pragma unroll
    for (int i = 0; i < 8; ++i) { f32x4 zz = {0.f,0.f,0.f,0.f}; acc[i] = zz; }
    mfma_tile(ldsEF, ldsW, acc, w, quad, n16);         // S1: pe

    // S2: edge score + sE (per head = per ct)
#pragma unroll
    for (int r = 0; r < 4; ++r) {
        int e = m0 + w * 16 + quad * 4 + r;
        int si = srcI[e], di = dstI[e];
        size_t sb = (size_t)si * 128, db = (size_t)di * 128;
#pragma unroll
        for (int ct = 0; ct < 8; ++ct) {
            int f = ct * 16 + n16;
            float sc = bf2f(K16[sb + f]) * bf2f(Q16[db + f]) * 0.25f * acc[ct][r];
            acc[ct][r] = sc;
            float hs = sc;
            hs += __shfl_xor(hs, 1); hs += __shfl_xor(hs, 2);
            hs += __shfl_xor(hs, 4); hs += __shfl_xor(hs, 8);
            if (n16 == 0) sE[(size_t)e * 8 + ct] = __expf(fminf(fmaxf(hs, -5.f), 5.f));
        }
    }

    __syncthreads();                                   // B1
    stage_bw(OeT, 128, ldsW, w, quad, n16);
    cwrite_lds(acc, ldsX, w, quad, n16);               // eo (bf16)
    __syncthreads();                                   // B2

    // S4: t = eo @ Oe
#pragma unroll
    for (int i = 0; i < 8; ++i) { f32x4 zz = {0.f,0.f,0.f,0.f}; acc[i] = zz; }
    mfma_tile(ldsX, ldsW, acc, w, quad, n16);

    // S5: ef1 = LN1(ef + t + Oe_b), in-register
    {
        float ob[8], g1[8], b1[8];
#pragma unroll
        for (int ct = 0; ct < 8; ++ct) {
            int col = ct * 16 + n16;
            ob[ct] = Oe_b[col]; g1[ct] = ln1e_g[col]; b1[ct] = ln1e_b[col];
        }
#pragma unroll
        for (int r = 0; r < 4; ++r) {
            int rl = w * 16 + quad * 4 + r;
            float v[8]; float s = 0.f, q = 0.f;
#pragma unroll
            for (int ct = 0; ct < 8; ++ct) {
                int col = ct * 16 + n16;
                float x = acc[ct][r] + ob[ct] + lds_at(ldsEF, rl, col);
                v[ct] = x; s += x; q += x * x;
            }
            s += __shfl_xor(s, 1); q += __shfl_xor(q, 1);
            s += __shfl_xor(s, 2); q += __shfl_xor(q, 2);
            s += __shfl_xor(s, 4); q += __shfl_xor(q, 4);
            s += __shfl_xor(s, 8); q += __shfl_xor(q, 8);
            float mean = s * (1.f / 128.f);
            float var  = q * (1.f / 128.f) - mean * mean;
            float inv  = rsqrtf(var + 1e-5f);
#pragma unroll
            for (int ct = 0; ct < 8; ++ct)
                acc[ct][r] = (v[ct] - mean) * inv * g1[ct] + b1[ct];
        }
    }

    __syncthreads();                                   // C1
    cwrite_lds(acc, ldsX, w, quad, n16);               // ef1 (bf16)
    stage_bw(Fe1T, 128, ldsW, w, quad, n16);           // Fe1 hidden cols 0..127
    __syncthreads();                                   // C2

    f32x4 acc3[8];
#pragma unroll
    for (int i = 0; i < 8; ++i) { f32x4 zz = {0.f,0.f,0.f,0.f}; acc3[i] = zz; }

    // S7: H0 = relu(ef1@Fe1[:,0:128] + b)
    f32x4 accH[8];
#pragma unroll
    for (int i = 0; i < 8; ++i) { f32x4 zz = {0.f,0.f,0.f,0.f}; accH[i] = zz; }
    mfma_tile(ldsX, ldsW, accH, w, quad, n16);
#pragma unroll
    for (int ct = 0; ct < 8; ++ct) {
        float bb = Fe1_b[ct * 16 + n16];
#pragma unroll
        for (int r = 0; r < 4; ++r) accH[ct][r] = fmaxf(accH[ct][r] + bb, 0.f);
    }
    __syncthreads();                                   // D1
    cwrite_lds(accH, ldsEF, w, quad, n16);             // H0
    stage_bw(Fe2T, 256, ldsW, w, quad, n16);           // Fe2 K-chunk 0
    __syncthreads();                                   // D2

    mfma_tile(ldsEF, ldsW, acc3, w, quad, n16);        // S9: acc3 += H0@Fe2c0

    __syncthreads();                                   // E1
    stage_bw(Fe1T + 128 * 128, 128, ldsW, w, quad, n16);  // Fe1 hidden cols 128..255
    __syncthreads();                                   // E2

    // S11: H1
#pragma unroll
    for (int i = 0; i < 8; ++i) { f32x4 zz = {0.f,0.f,0.f,0.f}; accH[i] = zz; }
    mfma_tile(ldsX, ldsW, accH, w, quad, n16);
#pragma unroll
    for (int ct = 0; ct < 8; ++ct) {
        float bb = Fe1_b[128 + ct * 16 + n16];
#pragma unroll
        for (int r = 0; r < 4; ++r) accH[ct][r] = fmaxf(accH[ct][r] + bb, 0.f);
    }
    __syncthreads();                                   // F1
    cwrite_lds(accH, ldsEF, w, quad, n16);             // H1
    stage_bw(Fe2T + 128, 256, ldsW, w, quad, n16);     // Fe2 K-chunk 1
    __syncthreads();                                   // F2

    mfma_tile(ldsEF, ldsW, acc3, w, quad, n16);        // S13: acc3 += H1@Fe2c1

    // S14: out = LN2(ef1 + acc3 + Fe2_b) -> fp32
    {
        float fb[8], g2[8], b2[8];
#pragma unroll
        for (int ct = 0; ct < 8; ++ct) {
            int col = ct * 16 + n16;
            fb[ct] = Fe2_b[col]; g2[ct] = ln2e_g[col]; b2[ct] = ln2e_b[col];
        }
#pragma unroll
        for (int r = 0; r < 4; ++r) {
            int rl = w * 16 + quad * 4 + r;
            float v[8]; float s = 0.f, q = 0.f;
#pragma unroll
            for (int ct = 0; ct < 8; ++ct) {
                int col = ct * 16 + n16;
                float x = acc3[ct][r] + fb[ct] + lds_at(ldsX, rl, col);
                v[ct] = x; s += x; q += x * x;
            }
            s += __shfl_xor(s, 1); q += __shfl_xor(q, 1);
            s += __shfl_xor(s, 2); q += __shfl_xor(q, 2);
            s += __shfl_xor(s, 4); q += __shfl_xor(q, 4);
            s += __shfl_xor(s, 8); q += __shfl_xor(q, 8);
            float mean = s * (1.f / 128.f);
            float var  = q * (1.f / 128.f) - mean * mean;
            float inv  = rsqrtf(var + 1e-5f);
#pragma unroll
            for (int ct = 0; ct < 8; ++ct) {
                int col = ct * 16 + n16;
                outEf[(size_t)(m0 + rl) * 128 + col] = (v[ct] - mean) * inv * g2[ct] + b2[ct];
            }
        }
    }
}

// -------------------- dst-CSR build (replaces wV/z atomics) -----------------
__global__ void hist_k(const int* __restrict__ dst, int* __restrict__ cnt, int n) {
    int i = blockIdx.x * 256 + threadIdx.x;
    if (i < n) atomicAdd(&cnt[dst[i]], 1);
}

__global__ __launch_bounds__(1024) void scan_k(
    const int* __restrict__ cnt, int* __restrict__ rowptr, int* __restrict__ cursor)
{
    __shared__ int part[1024];
    const int NBINS = 30000, PER = 30;
    int t = threadIdx.x;
    int base = t * PER;
    int s = 0;
    for (int j = 0; j < PER; ++j) {
        int b = base + j;
        s += (b < NBINS) ? cnt[b] : 0;
    }
    part[t] = s;
    __syncthreads();
    for (int off = 1; off < 1024; off <<= 1) {
        int x = (t >= off) ? part[t - off] : 0;
        __syncthreads();
        part[t] += x;
        __syncthreads();
    }
    int run = part[t] - s;  // exclusive prefix of this thread's chunk
    for (int j = 0; j < PER; ++j) {
        int b = base + j;
        if (b < NBINS) {
            rowptr[b] = run; cursor[b] = run;
            run += cnt[b];
        }
    }
    if (t == 1023) rowptr[NBINS] = part[1023];
}

__global__ void scatter_k(const int* __restrict__ dst, int* __restrict__ cursor,
                          int* __restrict__ eid, int n) {
    int i = blockIdx.x * 256 + threadIdx.x;
    if (i < n) { int p = atomicAdd(&cursor[dst[i]], 1); eid[p] = i; }
}

// h_att[n] = sum_{e in CSR(n)} V[src(e)]*s[e][h] / (sum s + 1e-6)  -> bf16
__global__ __launch_bounds__(256) void gather_k(
    const int* __restrict__ rowptr, const int* __restrict__ eid,
    const int* __restrict__ srcI, const float* __restrict__ sE,
    const short* __restrict__ V16, short* __restrict__ hatt)
{
    const int w = threadIdx.x >> 6, l = threadIdx.x & 63;
    const int n = blockIdx.x * 4 + w;
    if (n >= 30000) return;
    const int beg = rowptr[n], end = rowptr[n + 1];
    const int h = l >> 4;
    float a0 = 0.f, a1 = 0.f, z0 = 0.f, z1 = 0.f;
    for (int i = beg; i < end; ++i) {
        int e = eid[i];
        int si = srcI[e];
        float s0 = sE[(size_t)e * 8 + h];
        float s1 = sE[(size_t)e * 8 + 4 + h];
        float v0 = bf2f(V16[(size_t)si * 128 + l]);
        float v1 = bf2f(V16[(size_t)si * 128 + 64 + l]);
        a0 += v0 * s0; a1 += v1 * s1; z0 += s0; z1 += s1;
    }
    hatt[(size_t)n * 128 + l]      = f2bf(a0 / (z0 + 1e-6f));
    hatt[(size_t)n * 128 + 64 + l] = f2bf(a1 / (z1 + 1e-6f));
}

// softmax over 500 valid cols of lp[row][512], write fp32 (ld 500) + bf16 (ld 512, pad 0)
__global__ __launch_bounds__(256) void softmax_k(
    const float* __restrict__ lp, float* __restrict__ outF, short* __restrict__ lg16)
{
    const int tid = threadIdx.x;
    const int w = tid >> 6, l = tid & 63;
    const int row = blockIdx.x * 4 + w;
    const float scale = 0.088388347648318447f;  // 1/sqrt(128)
    float x[8];
#pragma unroll
    for (int j = 0; j < 8; ++j) {
        int c = l + 64 * j;
        x[j] = (c < 500) ? lp[(size_t)row * 512 + c] * scale : -1e30f;
    }
    float m = x[0];
#pragma unroll
    for (int j = 1; j < 8; ++j) m = fmaxf(m, x[j]);
#pragma unroll
    for (int k = 1; k < 64; k <<= 1) m = fmaxf(m, __shfl_xor(m, k));
    float e[8]; float s = 0.f;
#pragma unroll
    for (int j = 0; j < 8; ++j) { int c = l + 64 * j; e[j] = (c < 500) ? __expf(x[j] - m) : 0.f; s += e[j]; }
#pragma unroll
    for (int k = 1; k < 64; k <<= 1) s += __shfl_xor(s, k);
    float inv = 1.f / s;
#pragma unroll
    for (int j = 0; j < 8; ++j) {
        int c = l + 64 * j;
        float pv = e[j] * inv;
        lg16[(size_t)row * 512 + c] = f2bf(pv);
        if (c < 500) outF[(size_t)row * 500 + c] = pv;
    }
}

__global__ void f2b4_k(const float* __restrict__ in, short* __restrict__ out, int n4) {
    int i = blockIdx.x * 256 + threadIdx.x;
    if (i < n4) {
        f32x4 v = ((const f32x4*)in)[i];
        short4v o = { f2bf(v.x), f2bf(v.y), f2bf(v.z), f2bf(v.w) };
        ((short4v*)out)[i] = o;
    }
}

struct PrepArgs { const float* s[14]; short* d[14]; int K[14]; int N[14]; };
// convert weights fp32 [K][N] -> bf16 transposed [N][K]
__global__ void prep_w_k(PrepArgs a) {
    int m = blockIdx.y;
    int K = a.K[m], N = a.N[m];
    int i = blockIdx.x * 256 + threadIdx.x;
    if (i < K * N) {
        int k = i / N, n = i - k * N;
        a.d[m][n * K + k] = f2bf(a.s[m][i]);
    }
}

// k = word_feats@ca_k -> k16[512][128] (rows>=500 zero); v -> vT16[128][512] transposed
__global__ void ca_kv_k(const float* __restrict__ wf, const float* __restrict__ cak,
                        const float* __restrict__ cav, short* __restrict__ k16, short* __restrict__ vT16) {
    int kw = blockIdx.x, n = threadIdx.x;
    if (kw >= 500) { k16[kw * 128 + n] = 0; vT16[n * 512 + kw] = 0; return; }
    float ak = 0.f, av = 0.f;
    for (int t = 0; t < 300; ++t) {
        float wv = wf[kw * 300 + t];
        ak += wv * cak[t * 128 + n];
        av += wv * cav[t * 128 + n];
    }
    k16[kw * 128 + n] = f2bf(ak);
    vT16[n * 512 + kw] = f2bf(av);
}

extern "C" void kernel_launch(void* const* d_in, const int* in_sizes, int n_in,
                              void* d_out, int out_size, void* d_ws, size_t ws_size,
                              hipStream_t stream)
{
    const int N = 30000, E = 480000;
    const float* node_feats = (const float*)d_in[0];
    const float* edge_feats = (const float*)d_in[1];
    const float* word_feats = (const float*)d_in[2];
    const int*   srcI = (const int*)d_in[3];
    const int*   dstI = (const int*)d_in[4];
    const float* Wq = (const float*)d_in[5];
    const float* Wk = (const float*)d_in[6];
    const float* Wv = (const float*)d_in[7];
    const float* We = (const float*)d_in[8];
    const float* Oh_w = (const float*)d_in[9];
    const float* Oh_b = (const float*)d_in[10];
    const float* Oe_w = (const float*)d_in[11];
    const float* Oe_b = (const float*)d_in[12];
    const float* ln1h_g = (const float*)d_in[13];
    const float* ln1h_b = (const float*)d_in[14];
    const float* ln1e_g = (const float*)d_in[15];
    const float* ln1e_b = (const float*)d_in[16];
    const float* Fh1_w = (const float*)d_in[17];
    const float* Fh1_b = (const float*)d_in[18];
    const float* Fh2_w = (const float*)d_in[19];
    const float* Fh2_b = (const float*)d_in[20];
    const float* Fe1_w = (const float*)d_in[21];
    const float* Fe1_b = (const float*)d_in[22];
    const float* Fe2_w = (const float*)d_in[23];
    const float* Fe2_b = (const float*)d_in[24];
    const float* ln2h_g = (const float*)d_in[25];
    const float* ln2h_b = (const float*)d_in[26];
    const float* ln2e_g = (const float*)d_in[27];
    const float* ln2e_b = (const float*)d_in[28];
    const float* ca_q = (const float*)d_in[29];
    const float* ca_k = (const float*)d_in[30];
    const float* ca_v = (const float*)d_in[31];
    const float* ca_att = (const float*)d_in[32];
    const float* ca_ln1_g = (const float*)d_in[33];
    const float* ca_ln1_b = (const float*)d_in[34];
    const float* ca_ln2_g = (const float*)d_in[35];
    const float* ca_ln2_b = (const float*)d_in[36];
    const float* ca_f1 = (const float*)d_in[37];
    const float* ca_f2 = (const float*)d_in[38];

    float* outLogits = (float*)d_out;                    // [30000][500]
    float* outNf = (float*)d_out + 15000000;             // [30000][128]
    float* outEf = (float*)d_out + 18840000;             // [480000][128]

    char* ws = (char*)d_ws;
    size_t off = 0;
    auto alloc = [&](size_t b) -> char* { size_t o = off; off += (b + 255) & ~(size_t)255; return ws + o; };

    short* nf16   = (short*)alloc((size_t)N * 128 * 2);
    short* WqT    = (short*)alloc(16384 * 2);
    short* WkT    = (short*)alloc(16384 * 2);
    short* WvT    = (short*)alloc(16384 * 2);
    short* WeT    = (short*)alloc(16384 * 2);
    short* OhT    = (short*)alloc(16384 * 2);
    short* OeT    = (short*)alloc(16384 * 2);
    short* caqT   = (short*)alloc(16384 * 2);
    short* caattT = (short*)alloc(16384 * 2);
    short* Fh1T   = (short*)alloc(32768 * 2);
    short* Fe1T   = (short*)alloc(32768 * 2);
    short* caf1T  = (short*)alloc(32768 * 2);
    short* Fh2T   = (short*)alloc(32768 * 2);
    short* Fe2T   = (short*)alloc(32768 * 2);
    short* caf2T  = (short*)alloc(32768 * 2);
    short* k16    = (short*)alloc(512 * 128 * 2);
    short* vT16   = (short*)alloc(128 * 512 * 2);
    short* Q16    = (short*)alloc((size_t)N * 128 * 2);
    short* Kt16   = (short*)alloc((size_t)N * 128 * 2);
    short* V16    = (short*)alloc((size_t)N * 128 * 2);
    float* sE     = (float*)alloc((size_t)E * 8 * 4);    // per-(edge,head) exp score
    int*   cnt    = (int*)alloc((size_t)N * 4);
    int*   rowptr = (int*)alloc((size_t)(N + 1) * 4);
    int*   cursor = (int*)alloc((size_t)N * 4);
    int*   eid    = (int*)alloc((size_t)E * 4);
    short* hatt16 = (short*)alloc((size_t)N * 128 * 2);
    short* hf1_16 = (short*)alloc((size_t)N * 128 * 2);
    short* hf2_16 = (short*)alloc((size_t)N * 128 * 2);
    short* q16    = (short*)alloc((size_t)N * 128 * 2);
    short* attv16 = (short*)alloc((size_t)N * 128 * 2);
    short* nf1_16 = (short*)alloc((size_t)N * 128 * 2);
    short* Hc16   = (short*)alloc((size_t)N * 256 * 2);
    short* Hh16   = (short*)alloc((size_t)N * 256 * 2);
    char*  R1     = alloc((size_t)N * 512 * 4 + (size_t)N * 512 * 2);  // lp fp32 + lg16 bf16
    float* lp     = (float*)R1;                          // [30000][512] fp32
    short* lg16   = (short*)(R1 + (size_t)N * 512 * 4);  // [30000][512] bf16

    // zero dst histogram
    hipMemsetAsync(cnt, 0, (size_t)N * 4, stream);

    // convert node activations to bf16 (edge feats consumed fp32 by fused kernel)
    f2b4_k<<<dim3((N * 128 / 4 + 255) / 256), 256, 0, stream>>>(node_feats, nf16, N * 128 / 4);

    // prep weights (transpose + bf16)
    PrepArgs pa;
    const float* srcs[14] = {Wq, Wk, Wv, We, Oh_w, Oe_w, ca_q, ca_att, Fh1_w, Fe1_w, ca_f1, Fh2_w, Fe2_w, ca_f2};
    short* dsts[14] = {WqT, WkT, WvT, WeT, OhT, OeT, caqT, caattT, Fh1T, Fe1T, caf1T, Fh2T, Fe2T, caf2T};
    int Ks[14] = {128,128,128,128,128,128,128,128, 128,128,128, 256,256,256};
    int Ns[14] = {128,128,128,128,128,128,128,128, 256,256,256, 128,128,128};
    for (int i = 0; i < 14; ++i) { pa.s[i] = srcs[i]; pa.d[i] = dsts[i]; pa.K[i] = Ks[i]; pa.N[i] = Ns[i]; }
    prep_w_k<<<dim3(128, 14), 256, 0, stream>>>(pa);

    ca_kv_k<<<dim3(512), 128, 0, stream>>>(word_feats, ca_k, ca_v, k16, vT16);

    // dst-CSR build
    hist_k<<<dim3((E + 255) / 256), 256, 0, stream>>>(dstI, cnt, E);
    scan_k<<<dim3(1), 1024, 0, stream>>>(cnt, rowptr, cursor);
    scatter_k<<<dim3((E + 255) / 256), 256, 0, stream>>>(dstI, cursor, eid, E);

    const int NB = (N + 63) / 64;   // 469
    const int EB = E / 64;          // 7500

    // Q,K,V = nf @ W  -> bf16
    gemm_epi<false,false,false,false,false,true><<<dim3(NB,1),256,0,stream>>>(nf16, WqT, N, 128, nullptr, nullptr, nullptr, nullptr, nullptr, 0, Q16, 128);
    gemm_epi<false,false,false,false,false,true><<<dim3(NB,1),256,0,stream>>>(nf16, WkT, N, 128, nullptr, nullptr, nullptr, nullptr, nullptr, 0, Kt16, 128);
    gemm_epi<false,false,false,false,false,true><<<dim3(NB,1),256,0,stream>>>(nf16, WvT, N, 128, nullptr, nullptr, nullptr, nullptr, nullptr, 0, V16, 128);

    // fused edge chain: score+sE, Oe+LN1, FFN, LN2 -> outEf
    edge_fused_k<<<dim3(EB),256,0,stream>>>(edge_feats, WeT, Q16, Kt16, srcI, dstI,
                                            OeT, Oe_b, ln1e_g, ln1e_b,
                                            Fe1T, Fe1_b, Fe2T, Fe2_b, ln2e_g, ln2e_b,
                                            sE, outEf);

    // h_att via CSR gather
    gather_k<<<dim3((N + 3) / 4), 256, 0, stream>>>(rowptr, eid, srcI, sE, V16, hatt16);

    // node side
    gemm_epi<true,false,true,true,false,true><<<dim3(NB,1),256,0,stream>>>(hatt16, OhT, N, 128, Oh_b, nf16, ln1h_g, ln1h_b, nullptr, 0, hf1_16, 128);
    gemm_epi<true,true,false,false,false,true><<<dim3(NB,2),256,0,stream>>>(hf1_16, Fh1T, N, 128, Fh1_b, nullptr, nullptr, nullptr, nullptr, 0, Hh16, 256);
    gemm_epi<true,false,true,true,false,true><<<dim3(NB,1),256,0,stream>>>(Hh16, Fh2T, N, 256, Fh2_b, hf1_16, ln2h_g, ln2h_b, nullptr, 0, hf2_16, 128);

    // cross-attention
    gemm_epi<false,false,false,false,false,true><<<dim3(NB,1),256,0,stream>>>(hf2_16, caqT, N, 128, nullptr, nullptr, nullptr, nullptr, nullptr, 0, q16, 128);
    gemm_epi<false,false,false,false,true,false><<<dim3(NB,4),256,0,stream>>>(q16, k16, N, 128, nullptr, nullptr, nullptr, nullptr, lp, 512, nullptr, 0);
    softmax_k<<<dim3(N / 4), 256, 0, stream>>>(lp, outLogits, lg16);
    gemm_epi<false,false,false,false,false,true><<<dim3(NB,1),256,0,stream>>>(lg16, vT16, N, 512, nullptr, nullptr, nullptr, nullptr, nullptr, 0, attv16, 128);
    gemm_epi<false,false,true,true,false,true><<<dim3(NB,1),256,0,stream>>>(attv16, caattT, N, 128, nullptr, hf2_16, ca_ln1_g, ca_ln1_b, nullptr, 0, nf1_16, 128);
    gemm_epi<false,true,false,false,false,true><<<dim3(NB,2),256,0,stream>>>(nf1_16, caf1T, N, 128, nullptr, nullptr, nullptr, nullptr, nullptr, 0, Hc16, 256);
    gemm_epi<false,false,true,true,true,false><<<dim3(NB,1),256,0,stream>>>(Hc16, caf2T, N, 256, nullptr, nf1_16, ca_ln2_g, ca_ln2_b, outNf, 128, nullptr, 0);
}

// Round 5
// 1373.216 us; speedup vs baseline: 1.1834x; 1.0906x over previous
//
#include <hip/hip_runtime.h>
#include <stdint.h>

#define DEVI __device__ __forceinline__

typedef __attribute__((ext_vector_type(8))) short short8;
typedef __attribute__((ext_vector_type(4))) short short4v;
typedef __attribute__((ext_vector_type(4))) float f32x4;
typedef __attribute__((ext_vector_type(2))) float f32x2;

DEVI float bf2f(short s) { union { float f; uint32_t u; } x; x.u = ((uint32_t)(uint16_t)s) << 16; return x.f; }
DEVI short f2bf(float f) { union { float f; uint32_t u; } x; x.f = f; uint32_t r = x.u + 0x7fffu + ((x.u >> 16) & 1u); return (short)(r >> 16); }

// LDS-only barrier: commit ds ops, sync, but leave global loads in flight
// (cross-wave LDS sharing in edge_fused_k is ONLY the weight buffer).
#define BAR() do { asm volatile("s_waitcnt lgkmcnt(0)" ::: "memory"); \
                   __builtin_amdgcn_s_barrier(); \
                   asm volatile("" ::: "memory"); } while (0)

// ---------------------------------------------------------------------------
// Generic 64x128-tile bf16 MFMA GEMM: out = epi(A[M,K] @ Bt[N,K]^T)
// (used for node-side + cross-attention chains)
// ---------------------------------------------------------------------------
template<bool HB, bool RELU, bool LN, bool RES, bool OF, bool OB>
__global__ __launch_bounds__(256) void gemm_epi(
    const short* __restrict__ A, const short* __restrict__ Bt,
    int M, int K,
    const float* __restrict__ bias,
    const short* __restrict__ res16,
    const float* __restrict__ gamma, const float* __restrict__ beta,
    float* __restrict__ outF, int ldF,
    short* __restrict__ out16, int ld16)
{
    __shared__ char smem[49152];
    short* ldsA = (short*)smem;            // [64][128] shorts, swizzled granules
    short* ldsB = (short*)(smem + 16384);  // [128][128]
    float* ldsE = (float*)smem;            // epilogue [64][132]

    const int tid = threadIdx.x;
    const int w = tid >> 6, l = tid & 63;
    const int quad = l >> 4, n16 = l & 15;
    const int m0 = blockIdx.x * 64;
    const int n0 = blockIdx.y * 128;

    f32x4 acc[8];
#pragma unroll
    for (int i = 0; i < 8; ++i) { f32x4 zz = {0.f, 0.f, 0.f, 0.f}; acc[i] = zz; }

    const int nch = K >> 7;
    for (int c = 0; c < nch; ++c) {
#pragma unroll
        for (int ii = 0; ii < 4; ++ii) {
            int rl = (w * 4 + ii) * 4 + quad;
            int row = m0 + rl; if (row >= M) row = M - 1;
            int g = n16 ^ (rl & 15);
            short8 v = *(const short8*)(A + (size_t)row * K + c * 128 + g * 8);
            *(short8*)(ldsA + rl * 128 + n16 * 8) = v;
        }
#pragma unroll
        for (int jj = 0; jj < 8; ++jj) {
            int nl = (w * 8 + jj) * 4 + quad;
            int g = n16 ^ (nl & 15);
            short8 v = *(const short8*)(Bt + (size_t)(n0 + nl) * K + c * 128 + g * 8);
            *(short8*)(ldsB + nl * 128 + n16 * 8) = v;
        }
        __syncthreads();
#pragma unroll
        for (int kk = 0; kk < 4; ++kk) {
            int gi = kk * 4 + quad;
            short8 a = *(const short8*)(ldsA + (w * 16 + n16) * 128 + (gi ^ n16) * 8);
#pragma unroll
            for (int ct = 0; ct < 8; ++ct) {
                short8 b = *(const short8*)(ldsB + (ct * 16 + n16) * 128 + (gi ^ n16) * 8);
                acc[ct] = __builtin_amdgcn_mfma_f32_16x16x32_bf16(a, b, acc[ct], 0, 0, 0);
            }
        }
        __syncthreads();
    }

    // stage C tile to LDS (fp32, padded stride 132) for row-wise epilogue
#pragma unroll
    for (int ct = 0; ct < 8; ++ct)
#pragma unroll
        for (int r = 0; r < 4; ++r)
            ldsE[(w * 16 + quad * 4 + r) * 132 + ct * 16 + n16] = acc[ct][r];
    __syncthreads();

    const int rl = tid >> 2, p = tid & 3;
    const int row = m0 + rl;
    const bool valid = row < M;
    const int cb = p * 32;
    float v[32];
#pragma unroll
    for (int j = 0; j < 32; ++j) v[j] = ldsE[rl * 132 + cb + j];
    if (HB) {
#pragma unroll
        for (int j = 0; j < 32; ++j) v[j] += bias[n0 + cb + j];
    }
    if (RES) {
        if (valid) {
#pragma unroll
            for (int j = 0; j < 32; ++j) v[j] += bf2f(res16[(size_t)row * 128 + cb + j]);
        }
    }
    if (RELU) {
#pragma unroll
        for (int j = 0; j < 32; ++j) v[j] = fmaxf(v[j], 0.f);
    }
    if (LN) {  // N==128 required: full row in block
        float s = 0.f, q = 0.f;
#pragma unroll
        for (int j = 0; j < 32; ++j) { s += v[j]; q += v[j] * v[j]; }
        s += __shfl_xor(s, 1); q += __shfl_xor(q, 1);
        s += __shfl_xor(s, 2); q += __shfl_xor(q, 2);
        float mean = s * (1.f / 128.f);
        float var = q * (1.f / 128.f) - mean * mean;
        float inv = rsqrtf(var + 1e-5f);
#pragma unroll
        for (int j = 0; j < 32; ++j) v[j] = (v[j] - mean) * inv * gamma[cb + j] + beta[cb + j];
    }
    if (valid) {
        if (OF) {
#pragma unroll
            for (int jj = 0; jj < 8; ++jj) {
                f32x4 t = { v[jj*4], v[jj*4+1], v[jj*4+2], v[jj*4+3] };
                *(f32x4*)(outF + (size_t)row * ldF + n0 + cb + jj * 4) = t;
            }
        }
        if (OB) {
#pragma unroll
            for (int jj = 0; jj < 8; ++jj) {
                short4v t = { f2bf(v[jj*4]), f2bf(v[jj*4+1]), f2bf(v[jj*4+2]), f2bf(v[jj*4+3]) };
                *(short4v*)(out16 + (size_t)row * ld16 + n0 + cb + jj * 4) = t;
            }
        }
    }
}

// ------------------------- fused edge chain helpers -------------------------
// weight tile: load global -> regs (prefetch), store regs -> LDS later
DEVI void wload(const short* __restrict__ src, int ldK, short8* reg,
                int w, int quad, int n16) {
#pragma unroll
    for (int jj = 0; jj < 8; ++jj) {
        int nl = (w * 8 + jj) * 4 + quad;
        int g = n16 ^ (nl & 15);
        reg[jj] = *(const short8*)(src + (size_t)nl * ldK + g * 8);
    }
}
DEVI void wstore(const short8* reg, short* lds, int w, int quad, int n16) {
#pragma unroll
    for (int jj = 0; jj < 8; ++jj) {
        int nl = (w * 8 + jj) * 4 + quad;
        *(short8*)(lds + nl * 128 + n16 * 8) = reg[jj];
    }
}

DEVI void mfma_tile(const short* ldsA, const short* ldsB, f32x4* acc,
                    int w, int quad, int n16) {
#pragma unroll
    for (int kk = 0; kk < 4; ++kk) {
        int gi = kk * 4 + quad;
        short8 a = *(const short8*)(ldsA + (w * 16 + n16) * 128 + ((gi ^ n16)) * 8);
#pragma unroll
        for (int ct = 0; ct < 8; ++ct) {
            short8 b = *(const short8*)(ldsB + (ct * 16 + n16) * 128 + ((gi ^ n16)) * 8);
            acc[ct] = __builtin_amdgcn_mfma_f32_16x16x32_bf16(a, b, acc[ct], 0, 0, 0);
        }
    }
}

// write C-layout regs as bf16 swizzled A-tile ([64][128], granule g ^= row&15)
// NOTE: rows written/read are wave-private (w*16..w*16+15) -> no barrier needed
DEVI void cwrite_lds(const f32x4* acc, short* lds, int w, int quad, int n16) {
#pragma unroll
    for (int r = 0; r < 4; ++r) {
        int rl = w * 16 + quad * 4 + r;
#pragma unroll
        for (int ct = 0; ct < 8; ++ct) {
            int col = ct * 16 + n16;
            int gp = (col >> 3) ^ (rl & 15);
            lds[rl * 128 + gp * 8 + (col & 7)] = f2bf(acc[ct][r]);
        }
    }
}

DEVI float lds_at(const short* lds, int rl, int col) {
    int gp = (col >> 3) ^ (rl & 15);
    return bf2f(lds[rl * 128 + gp * 8 + (col & 7)]);
}

// ---------------------------------------------------------------------------
// Fused edge chain, one 64-edge tile per block, latency-hiding version:
//  - all global loads (ef rows, Q/K rows, weights) issued early into regs;
//    raw s_barrier (lgkmcnt-only) keeps them in flight across phases
//  - Q/K gathered as coalesced 16B row chunks; kq=K*Q fp32 redistributed
//    via the dead weight-buffer LDS (stride 132, conflict-free)
//  - A-tiles (ef/eo/ef1/H) are wave-private rows -> no barrier for them;
//    barriers only fence the shared weight buffer
// ---------------------------------------------------------------------------
__global__ __launch_bounds__(256) void edge_fused_k(
    const float* __restrict__ edge_feats, const short* __restrict__ WeT,
    const short* __restrict__ Q16, const short* __restrict__ K16,
    const int* __restrict__ srcI, const int* __restrict__ dstI,
    const short* __restrict__ OeT, const float* __restrict__ Oe_b,
    const float* __restrict__ ln1e_g, const float* __restrict__ ln1e_b,
    const short* __restrict__ Fe1T, const float* __restrict__ Fe1_b,
    const short* __restrict__ Fe2T, const float* __restrict__ Fe2_b,
    const float* __restrict__ ln2e_g, const float* __restrict__ ln2e_b,
    float* __restrict__ sE, float* __restrict__ outEf)
{
    __shared__ char smem[66560];
    short* ldsEF = (short*)smem;            // ef tile -> H halves (wave-private rows)
    short* ldsX  = (short*)(smem + 16384);  // eo -> ef1 tile (wave-private rows)
    short* ldsW  = (short*)(smem + 32768);  // shared weight buffer [128][128] bf16
    float* kqf   = (float*)(smem + 32768);  // kq fp32 [64][132] (aliases ldsW)

    const int tid = threadIdx.x;
    const int w = tid >> 6, l = tid & 63;
    const int quad = l >> 4, n16 = l & 15;
    const int m0 = blockIdx.x * 64;

    // ---------------- prefetch issues (oldest-first for vmcnt) ----------------
    f32x4 efr[8];
#pragma unroll
    for (int ii = 0; ii < 4; ++ii) {
        int rl = w * 16 + ii * 4 + quad;
        int g = n16 ^ (rl & 15);
        const float* src = edge_feats + (size_t)(m0 + rl) * 128 + g * 8;
        efr[ii * 2]     = *(const f32x4*)src;
        efr[ii * 2 + 1] = *(const f32x4*)(src + 4);
    }
    short8 wwe[8];
    wload(WeT, 128, wwe, w, quad, n16);
    int si_[4], di_[4];
#pragma unroll
    for (int r = 0; r < 4; ++r) {
        int e = m0 + w * 16 + quad * 4 + r;
        si_[r] = srcI[e]; di_[r] = dstI[e];
    }
    short8 kreg[4], qreg[4];
#pragma unroll
    for (int r = 0; r < 4; ++r) {
        kreg[r] = *(const short8*)(K16 + (size_t)si_[r] * 128 + n16 * 8);
        qreg[r] = *(const short8*)(Q16 + (size_t)di_[r] * 128 + n16 * 8);
    }
    short8 wA[8], wB[8];
    wload(OeT, 128, wA, w, quad, n16);          // Oe  (used phase 4)
    wload(Fe1T, 128, wB, w, quad, n16);         // Fe1 half0 (used phase 6)

    // ---------------- phase 0: EF + We -> LDS ----------------
#pragma unroll
    for (int ii = 0; ii < 4; ++ii) {
        int rl = w * 16 + ii * 4 + quad;
        f32x4 u0 = efr[ii * 2], u1 = efr[ii * 2 + 1];
        short8 v = { f2bf(u0.x), f2bf(u0.y), f2bf(u0.z), f2bf(u0.w),
                     f2bf(u1.x), f2bf(u1.y), f2bf(u1.z), f2bf(u1.w) };
        *(short8*)(ldsEF + rl * 128 + n16 * 8) = v;
    }
    wstore(wwe, ldsW, w, quad, n16);
    BAR();  // 1: We visible

    f32x4 acc[8];
#pragma unroll
    for (int i = 0; i < 8; ++i) { f32x4 zz = {0.f,0.f,0.f,0.f}; acc[i] = zz; }
    mfma_tile(ldsEF, ldsW, acc, w, quad, n16);  // pe
    BAR();  // 2: all waves done reading We

    // kq fp32 into dead weight buffer (wave-private rows; same-wave read below)
#pragma unroll
    for (int r = 0; r < 4; ++r) {
        int rl = w * 16 + quad * 4 + r;
        f32x4 p0 = { bf2f(kreg[r][0]) * bf2f(qreg[r][0]),
                     bf2f(kreg[r][1]) * bf2f(qreg[r][1]),
                     bf2f(kreg[r][2]) * bf2f(qreg[r][2]),
                     bf2f(kreg[r][3]) * bf2f(qreg[r][3]) };
        f32x4 p1 = { bf2f(kreg[r][4]) * bf2f(qreg[r][4]),
                     bf2f(kreg[r][5]) * bf2f(qreg[r][5]),
                     bf2f(kreg[r][6]) * bf2f(qreg[r][6]),
                     bf2f(kreg[r][7]) * bf2f(qreg[r][7]) };
        *(f32x4*)(kqf + rl * 132 + n16 * 8)     = p0;
        *(f32x4*)(kqf + rl * 132 + n16 * 8 + 4) = p1;
    }
    // score: sc = kq * 0.25 * pe ; sE = exp(clip(head-sum)) stored as (h,h+4) pairs
#pragma unroll
    for (int r = 0; r < 4; ++r) {
        int rl = w * 16 + quad * 4 + r;
        int e = m0 + rl;
#pragma unroll
        for (int ct = 0; ct < 8; ++ct) {
            float sc = kqf[rl * 132 + ct * 16 + n16] * 0.25f * acc[ct][r];
            acc[ct][r] = sc;
            float hs = sc;
            hs += __shfl_xor(hs, 1); hs += __shfl_xor(hs, 2);
            hs += __shfl_xor(hs, 4); hs += __shfl_xor(hs, 8);
            if (n16 == 0) {
                float s = __expf(fminf(fmaxf(hs, -5.f), 5.f));
                int pos = (ct < 4) ? (ct * 2) : ((ct - 4) * 2 + 1);
                sE[(size_t)e * 8 + pos] = s;
            }
        }
    }
    cwrite_lds(acc, ldsX, w, quad, n16);        // eo (wave-private)
    BAR();  // 3: kq region dead everywhere

    wstore(wA, ldsW, w, quad, n16);             // Oe -> LDS (from regs, no latency)
    wload(Fe2T, 256, wA, w, quad, n16);         // prefetch Fe2 half0
    BAR();  // 4: Oe visible

    f32x4 acc2[8];
#pragma unroll
    for (int i = 0; i < 8; ++i) { f32x4 zz = {0.f,0.f,0.f,0.f}; acc2[i] = zz; }
    mfma_tile(ldsX, ldsW, acc2, w, quad, n16);  // t = eo @ Oe

    // LN1: ef1 = LN(ef + t + Oe_b) in-register
    {
        float ob[8], g1[8], b1[8];
#pragma unroll
        for (int ct = 0; ct < 8; ++ct) {
            int col = ct * 16 + n16;
            ob[ct] = Oe_b[col]; g1[ct] = ln1e_g[col]; b1[ct] = ln1e_b[col];
        }
#pragma unroll
        for (int r = 0; r < 4; ++r) {
            int rl = w * 16 + quad * 4 + r;
            float v[8]; float s = 0.f, q = 0.f;
#pragma unroll
            for (int ct = 0; ct < 8; ++ct) {
                int col = ct * 16 + n16;
                float x = acc2[ct][r] + ob[ct] + lds_at(ldsEF, rl, col);
                v[ct] = x; s += x; q += x * x;
            }
            s += __shfl_xor(s, 1); q += __shfl_xor(q, 1);
            s += __shfl_xor(s, 2); q += __shfl_xor(q, 2);
            s += __shfl_xor(s, 4); q += __shfl_xor(q, 4);
            s += __shfl_xor(s, 8); q += __shfl_xor(q, 8);
            float mean = s * (1.f / 128.f);
            float var  = q * (1.f / 128.f) - mean * mean;
            float inv  = rsqrtf(var + 1e-5f);
#pragma unroll
            for (int ct = 0; ct < 8; ++ct)
                acc[ct][r] = (v[ct] - mean) * inv * g1[ct] + b1[ct];
        }
    }
    BAR();  // 5: Oe consumed by all

    cwrite_lds(acc, ldsX, w, quad, n16);        // ef1 (wave-private)
    wstore(wB, ldsW, w, quad, n16);             // Fe1 half0 -> LDS
    wload(Fe1T + 128 * 128, 128, wB, w, quad, n16);  // prefetch Fe1 half1
    BAR();  // 6

    f32x4 accH[8];
#pragma unroll
    for (int i = 0; i < 8; ++i) { f32x4 zz = {0.f,0.f,0.f,0.f}; accH[i] = zz; }
    mfma_tile(ldsX, ldsW, accH, w, quad, n16);  // H0
#pragma unroll
    for (int ct = 0; ct < 8; ++ct) {
        float bb = Fe1_b[ct * 16 + n16];
#pragma unroll
        for (int r = 0; r < 4; ++r) accH[ct][r] = fmaxf(accH[ct][r] + bb, 0.f);
    }
    cwrite_lds(accH, ldsEF, w, quad, n16);      // H0 (ef residual dead post-LN1)
    BAR();  // 7: Fe1 half0 consumed

    wstore(wA, ldsW, w, quad, n16);             // Fe2 half0 -> LDS
    wload(Fe2T + 128, 256, wA, w, quad, n16);   // prefetch Fe2 half1
    BAR();  // 8

    f32x4 acc3[8];
#pragma unroll
    for (int i = 0; i < 8; ++i) { f32x4 zz = {0.f,0.f,0.f,0.f}; acc3[i] = zz; }
    mfma_tile(ldsEF, ldsW, acc3, w, quad, n16); // += H0 @ Fe2c0
    BAR();  // 9: Fe2 half0 consumed

    wstore(wB, ldsW, w, quad, n16);             // Fe1 half1 -> LDS
    BAR();  // 10

#pragma unroll
    for (int i = 0; i < 8; ++i) { f32x4 zz = {0.f,0.f,0.f,0.f}; accH[i] = zz; }
    mfma_tile(ldsX, ldsW, accH, w, quad, n16);  // H1
#pragma unroll
    for (int ct = 0; ct < 8; ++ct) {
        float bb = Fe1_b[128 + ct * 16 + n16];
#pragma unroll
        for (int r = 0; r < 4; ++r) accH[ct][r] = fmaxf(accH[ct][r] + bb, 0.f);
    }
    cwrite_lds(accH, ldsEF, w, quad, n16);      // H1
    BAR();  // 11: Fe1 half1 consumed

    wstore(wA, ldsW, w, quad, n16);             // Fe2 half1 -> LDS
    BAR();  // 12

    mfma_tile(ldsEF, ldsW, acc3, w, quad, n16); // += H1 @ Fe2c1

    // LN2: out = LN(ef1 + acc3 + Fe2_b) -> fp32
    {
        float fb[8], g2[8], b2[8];
#pragma unroll
        for (int ct = 0; ct < 8; ++ct) {
            int col = ct * 16 + n16;
            fb[ct] = Fe2_b[col]; g2[ct] = ln2e_g[col]; b2[ct] = ln2e_b[col];
        }
#pragma unroll
        for (int r = 0; r < 4; ++r) {
            int rl = w * 16 + quad * 4 + r;
            float v[8]; float s = 0.f, q = 0.f;
#pragma unroll
            for (int ct = 0; ct < 8; ++ct) {
                int col = ct * 16 + n16;
                float x = acc3[ct][r] + fb[ct] + lds_at(ldsX, rl, col);
                v[ct] = x; s += x; q += x * x;
            }
            s += __shfl_xor(s, 1); q += __shfl_xor(q, 1);
            s += __shfl_xor(s, 2); q += __shfl_xor(q, 2);
            s += __shfl_xor(s, 4); q += __shfl_xor(q, 4);
            s += __shfl_xor(s, 8); q += __shfl_xor(q, 8);
            float mean = s * (1.f / 128.f);
            float var  = q * (1.f / 128.f) - mean * mean;
            float inv  = rsqrtf(var + 1e-5f);
#pragma unroll
            for (int ct = 0; ct < 8; ++ct) {
                int col = ct * 16 + n16;
                outEf[(size_t)(m0 + rl) * 128 + col] = (v[ct] - mean) * inv * g2[ct] + b2[ct];
            }
        }
    }
}

// -------------------- dst-CSR build (replaces wV/z atomics) -----------------
__global__ void hist_k(const int* __restrict__ dst, int* __restrict__ cnt, int n) {
    int i = blockIdx.x * 256 + threadIdx.x;
    if (i < n) atomicAdd(&cnt[dst[i]], 1);
}

__global__ __launch_bounds__(1024) void scan_k(
    const int* __restrict__ cnt, int* __restrict__ rowptr, int* __restrict__ cursor)
{
    __shared__ int part[1024];
    const int NBINS = 30000, PER = 30;
    int t = threadIdx.x;
    int base = t * PER;
    int s = 0;
    for (int j = 0; j < PER; ++j) {
        int b = base + j;
        s += (b < NBINS) ? cnt[b] : 0;
    }
    part[t] = s;
    __syncthreads();
    for (int off = 1; off < 1024; off <<= 1) {
        int x = (t >= off) ? part[t - off] : 0;
        __syncthreads();
        part[t] += x;
        __syncthreads();
    }
    int run = part[t] - s;  // exclusive prefix of this thread's chunk
    for (int j = 0; j < PER; ++j) {
        int b = base + j;
        if (b < NBINS) {
            rowptr[b] = run; cursor[b] = run;
            run += cnt[b];
        }
    }
    if (t == 1023) rowptr[NBINS] = part[1023];
}

__global__ void scatter_k(const int* __restrict__ dst, const int* __restrict__ srcA,
                          int* __restrict__ cursor,
                          int* __restrict__ eid, int* __restrict__ srcv, int n) {
    int i = blockIdx.x * 256 + threadIdx.x;
    if (i < n) {
        int p = atomicAdd(&cursor[dst[i]], 1);
        eid[p] = i; srcv[p] = srcA[i];
    }
}

// h_att[n] = sum_{e in CSR(n)} V[src(e)]*s[e][h] / (sum s + 1e-6)  -> bf16
// sE stored as (h, h+4) pairs -> one 8B read per edge
__global__ __launch_bounds__(256) void gather_k(
    const int* __restrict__ rowptr, const int* __restrict__ eid,
    const int* __restrict__ srcv, const float* __restrict__ sE,
    const short* __restrict__ V16, short* __restrict__ hatt)
{
    const int w = threadIdx.x >> 6, l = threadIdx.x & 63;
    const int n = blockIdx.x * 4 + w;
    if (n >= 30000) return;
    const int beg = rowptr[n], end = rowptr[n + 1];
    const int h = l >> 4;
    float a0 = 0.f, a1 = 0.f, z0 = 0.f, z1 = 0.f;
    for (int i = beg; i < end; ++i) {
        int e = eid[i];
        int si = srcv[i];
        f32x2 ss = *(const f32x2*)(sE + (size_t)e * 8 + h * 2);
        float v0 = bf2f(V16[(size_t)si * 128 + l]);
        float v1 = bf2f(V16[(size_t)si * 128 + 64 + l]);
        a0 += v0 * ss.x; a1 += v1 * ss.y; z0 += ss.x; z1 += ss.y;
    }
    hatt[(size_t)n * 128 + l]      = f2bf(a0 / (z0 + 1e-6f));
    hatt[(size_t)n * 128 + 64 + l] = f2bf(a1 / (z1 + 1e-6f));
}

// softmax over 500 valid cols of lp[row][512], write fp32 (ld 500) + bf16 (ld 512, pad 0)
__global__ __launch_bounds__(256) void softmax_k(
    const float* __restrict__ lp, float* __restrict__ outF, short* __restrict__ lg16)
{
    const int tid = threadIdx.x;
    const int w = tid >> 6, l = tid & 63;
    const int row = blockIdx.x * 4 + w;
    const float scale = 0.088388347648318447f;  // 1/sqrt(128)
    float x[8];
#pragma unroll
    for (int j = 0; j < 8; ++j) {
        int c = l + 64 * j;
        x[j] = (c < 500) ? lp[(size_t)row * 512 + c] * scale : -1e30f;
    }
    float m = x[0];
#pragma unroll
    for (int j = 1; j < 8; ++j) m = fmaxf(m, x[j]);
#pragma unroll
    for (int k = 1; k < 64; k <<= 1) m = fmaxf(m, __shfl_xor(m, k));
    float e[8]; float s = 0.f;
#pragma unroll
    for (int j = 0; j < 8; ++j) { int c = l + 64 * j; e[j] = (c < 500) ? __expf(x[j] - m) : 0.f; s += e[j]; }
#pragma unroll
    for (int k = 1; k < 64; k <<= 1) s += __shfl_xor(s, k);
    float inv = 1.f / s;
#pragma unroll
    for (int j = 0; j < 8; ++j) {
        int c = l + 64 * j;
        float pv = e[j] * inv;
        lg16[(size_t)row * 512 + c] = f2bf(pv);
        if (c < 500) outF[(size_t)row * 500 + c] = pv;
    }
}

__global__ void f2b4_k(const float* __restrict__ in, short* __restrict__ out, int n4) {
    int i = blockIdx.x * 256 + threadIdx.x;
    if (i < n4) {
        f32x4 v = ((const f32x4*)in)[i];
        short4v o = { f2bf(v.x), f2bf(v.y), f2bf(v.z), f2bf(v.w) };
        ((short4v*)out)[i] = o;
    }
}

struct PrepArgs { const float* s[14]; short* d[14]; int K[14]; int N[14]; };
// convert weights fp32 [K][N] -> bf16 transposed [N][K]
__global__ void prep_w_k(PrepArgs a) {
    int m = blockIdx.y;
    int K = a.K[m], N = a.N[m];
    int i = blockIdx.x * 256 + threadIdx.x;
    if (i < K * N) {
        int k = i / N, n = i - k * N;
        a.d[m][n * K + k] = f2bf(a.s[m][i]);
    }
}

// k = word_feats@ca_k -> k16[512][128] (rows>=500 zero); v -> vT16[128][512] transposed
__global__ void ca_kv_k(const float* __restrict__ wf, const float* __restrict__ cak,
                        const float* __restrict__ cav, short* __restrict__ k16, short* __restrict__ vT16) {
    int kw = blockIdx.x, n = threadIdx.x;
    if (kw >= 500) { k16[kw * 128 + n] = 0; vT16[n * 512 + kw] = 0; return; }
    float ak = 0.f, av = 0.f;
    for (int t = 0; t < 300; ++t) {
        float wv = wf[kw * 300 + t];
        ak += wv * cak[t * 128 + n];
        av += wv * cav[t * 128 + n];
    }
    k16[kw * 128 + n] = f2bf(ak);
    vT16[n * 512 + kw] = f2bf(av);
}

extern "C" void kernel_launch(void* const* d_in, const int* in_sizes, int n_in,
                              void* d_out, int out_size, void* d_ws, size_t ws_size,
                              hipStream_t stream)
{
    const int N = 30000, E = 480000;
    const float* node_feats = (const float*)d_in[0];
    const float* edge_feats = (const float*)d_in[1];
    const float* word_feats = (const float*)d_in[2];
    const int*   srcI = (const int*)d_in[3];
    const int*   dstI = (const int*)d_in[4];
    const float* Wq = (const float*)d_in[5];
    const float* Wk = (const float*)d_in[6];
    const float* Wv = (const float*)d_in[7];
    const float* We = (const float*)d_in[8];
    const float* Oh_w = (const float*)d_in[9];
    const float* Oh_b = (const float*)d_in[10];
    const float* Oe_w = (const float*)d_in[11];
    const float* Oe_b = (const float*)d_in[12];
    const float* ln1h_g = (const float*)d_in[13];
    const float* ln1h_b = (const float*)d_in[14];
    const float* ln1e_g = (const float*)d_in[15];
    const float* ln1e_b = (const float*)d_in[16];
    const float* Fh1_w = (const float*)d_in[17];
    const float* Fh1_b = (const float*)d_in[18];
    const float* Fh2_w = (const float*)d_in[19];
    const float* Fh2_b = (const float*)d_in[20];
    const float* Fe1_w = (const float*)d_in[21];
    const float* Fe1_b = (const float*)d_in[22];
    const float* Fe2_w = (const float*)d_in[23];
    const float* Fe2_b = (const float*)d_in[24];
    const float* ln2h_g = (const float*)d_in[25];
    const float* ln2h_b = (const float*)d_in[26];
    const float* ln2e_g = (const float*)d_in[27];
    const float* ln2e_b = (const float*)d_in[28];
    const float* ca_q = (const float*)d_in[29];
    const float* ca_k = (const float*)d_in[30];
    const float* ca_v = (const float*)d_in[31];
    const float* ca_att = (const float*)d_in[32];
    const float* ca_ln1_g = (const float*)d_in[33];
    const float* ca_ln1_b = (const float*)d_in[34];
    const float* ca_ln2_g = (const float*)d_in[35];
    const float* ca_ln2_b = (const float*)d_in[36];
    const float* ca_f1 = (const float*)d_in[37];
    const float* ca_f2 = (const float*)d_in[38];

    float* outLogits = (float*)d_out;                    // [30000][500]
    float* outNf = (float*)d_out + 15000000;             // [30000][128]
    float* outEf = (float*)d_out + 18840000;             // [480000][128]

    char* ws = (char*)d_ws;
    size_t off = 0;
    auto alloc = [&](size_t b) -> char* { size_t o = off; off += (b + 255) & ~(size_t)255; return ws + o; };

    short* nf16   = (short*)alloc((size_t)N * 128 * 2);
    short* WqT    = (short*)alloc(16384 * 2);
    short* WkT    = (short*)alloc(16384 * 2);
    short* WvT    = (short*)alloc(16384 * 2);
    short* WeT    = (short*)alloc(16384 * 2);
    short* OhT    = (short*)alloc(16384 * 2);
    short* OeT    = (short*)alloc(16384 * 2);
    short* caqT   = (short*)alloc(16384 * 2);
    short* caattT = (short*)alloc(16384 * 2);
    short* Fh1T   = (short*)alloc(32768 * 2);
    short* Fe1T   = (short*)alloc(32768 * 2);
    short* caf1T  = (short*)alloc(32768 * 2);
    short* Fh2T   = (short*)alloc(32768 * 2);
    short* Fe2T   = (short*)alloc(32768 * 2);
    short* caf2T  = (short*)alloc(32768 * 2);
    short* k16    = (short*)alloc(512 * 128 * 2);
    short* vT16   = (short*)alloc(128 * 512 * 2);
    short* Q16    = (short*)alloc((size_t)N * 128 * 2);
    short* Kt16   = (short*)alloc((size_t)N * 128 * 2);
    short* V16    = (short*)alloc((size_t)N * 128 * 2);
    float* sE     = (float*)alloc((size_t)E * 8 * 4);    // per-(edge,head) exp score, (h,h+4)-paired
    int*   cnt    = (int*)alloc((size_t)N * 4);
    int*   rowptr = (int*)alloc((size_t)(N + 1) * 4);
    int*   cursor = (int*)alloc((size_t)N * 4);
    int*   eid    = (int*)alloc((size_t)E * 4);
    int*   srcv   = (int*)alloc((size_t)E * 4);
    short* hatt16 = (short*)alloc((size_t)N * 128 * 2);
    short* hf1_16 = (short*)alloc((size_t)N * 128 * 2);
    short* hf2_16 = (short*)alloc((size_t)N * 128 * 2);
    short* q16    = (short*)alloc((size_t)N * 128 * 2);
    short* attv16 = (short*)alloc((size_t)N * 128 * 2);
    short* nf1_16 = (short*)alloc((size_t)N * 128 * 2);
    short* Hc16   = (short*)alloc((size_t)N * 256 * 2);
    short* Hh16   = (short*)alloc((size_t)N * 256 * 2);
    char*  R1     = alloc((size_t)N * 512 * 4 + (size_t)N * 512 * 2);  // lp fp32 + lg16 bf16
    float* lp     = (float*)R1;                          // [30000][512] fp32
    short* lg16   = (short*)(R1 + (size_t)N * 512 * 4);  // [30000][512] bf16

    // zero dst histogram
    hipMemsetAsync(cnt, 0, (size_t)N * 4, stream);

    // convert node activations to bf16 (edge feats consumed fp32 by fused kernel)
    f2b4_k<<<dim3((N * 128 / 4 + 255) / 256), 256, 0, stream>>>(node_feats, nf16, N * 128 / 4);

    // prep weights (transpose + bf16)
    PrepArgs pa;
    const float* srcs[14] = {Wq, Wk, Wv, We, Oh_w, Oe_w, ca_q, ca_att, Fh1_w, Fe1_w, ca_f1, Fh2_w, Fe2_w, ca_f2};
    short* dsts[14] = {WqT, WkT, WvT, WeT, OhT, OeT, caqT, caattT, Fh1T, Fe1T, caf1T, Fh2T, Fe2T, caf2T};
    int Ks[14] = {128,128,128,128,128,128,128,128, 128,128,128, 256,256,256};
    int Ns[14] = {128,128,128,128,128,128,128,128, 256,256,256, 128,128,128};
    for (int i = 0; i < 14; ++i) { pa.s[i] = srcs[i]; pa.d[i] = dsts[i]; pa.K[i] = Ks[i]; pa.N[i] = Ns[i]; }
    prep_w_k<<<dim3(128, 14), 256, 0, stream>>>(pa);

    ca_kv_k<<<dim3(512), 128, 0, stream>>>(word_feats, ca_k, ca_v, k16, vT16);

    // dst-CSR build
    hist_k<<<dim3((E + 255) / 256), 256, 0, stream>>>(dstI, cnt, E);
    scan_k<<<dim3(1), 1024, 0, stream>>>(cnt, rowptr, cursor);
    scatter_k<<<dim3((E + 255) / 256), 256, 0, stream>>>(dstI, srcI, cursor, eid, srcv, E);

    const int NB = (N + 63) / 64;   // 469
    const int EB = E / 64;          // 7500

    // Q,K,V = nf @ W  -> bf16
    gemm_epi<false,false,false,false,false,true><<<dim3(NB,1),256,0,stream>>>(nf16, WqT, N, 128, nullptr, nullptr, nullptr, nullptr, nullptr, 0, Q16, 128);
    gemm_epi<false,false,false,false,false,true><<<dim3(NB,1),256,0,stream>>>(nf16, WkT, N, 128, nullptr, nullptr, nullptr, nullptr, nullptr, 0, Kt16, 128);
    gemm_epi<false,false,false,false,false,true><<<dim3(NB,1),256,0,stream>>>(nf16, WvT, N, 128, nullptr, nullptr, nullptr, nullptr, nullptr, 0, V16, 128);

    // fused edge chain: score+sE, Oe+LN1, FFN, LN2 -> outEf
    edge_fused_k<<<dim3(EB),256,0,stream>>>(edge_feats, WeT, Q16, Kt16, srcI, dstI,
                                            OeT, Oe_b, ln1e_g, ln1e_b,
                                            Fe1T, Fe1_b, Fe2T, Fe2_b, ln2e_g, ln2e_b,
                                            sE, outEf);

    // h_att via CSR gather
    gather_k<<<dim3((N + 3) / 4), 256, 0, stream>>>(rowptr, eid, srcv, sE, V16, hatt16);

    // node side
    gemm_epi<true,false,true,true,false,true><<<dim3(NB,1),256,0,stream>>>(hatt16, OhT, N, 128, Oh_b, nf16, ln1h_g, ln1h_b, nullptr, 0, hf1_16, 128);
    gemm_epi<true,true,false,false,false,true><<<dim3(NB,2),256,0,stream>>>(hf1_16, Fh1T, N, 128, Fh1_b, nullptr, nullptr, nullptr, nullptr, 0, Hh16, 256);
    gemm_epi<true,false,true,true,false,true><<<dim3(NB,1),256,0,stream>>>(Hh16, Fh2T, N, 256, Fh2_b, hf1_16, ln2h_g, ln2h_b, nullptr, 0, hf2_16, 128);

    // cross-attention
    gemm_epi<false,false,false,false,false,true><<<dim3(NB,1),256,0,stream>>>(hf2_16, caqT, N, 128, nullptr, nullptr, nullptr, nullptr, nullptr, 0, q16, 128);
    gemm_epi<false,false,false,false,true,false><<<dim3(NB,4),256,0,stream>>>(q16, k16, N, 128, nullptr, nullptr, nullptr, nullptr, lp, 512, nullptr, 0);
    softmax_k<<<dim3(N / 4), 256, 0, stream>>>(lp, outLogits, lg16);
    gemm_epi<false,false,false,false,false,true><<<dim3(NB,1),256,0,stream>>>(lg16, vT16, N, 512, nullptr, nullptr, nullptr, nullptr, nullptr, 0, attv16, 128);
    gemm_epi<false,false,true,true,false,true><<<dim3(NB,1),256,0,stream>>>(attv16, caattT, N, 128, nullptr, hf2_16, ca_ln1_g, ca_ln1_b, nullptr, 0, nf1_16, 128);
    gemm_epi<false,true,false,false,false,true><<<dim3(NB,2),256,0,stream>>>(nf1_16, caf1T, N, 128, nullptr, nullptr, nullptr, nullptr, nullptr, 0, Hc16, 256);
    gemm_epi<false,false,true,true,true,false><<<dim3(NB,1),256,0,stream>>>(Hc16, caf2T, N, 256, nullptr, nf1_16, ca_ln2_g, ca_ln2_b, outNf, 128, nullptr, 0);
}